// Round 20
// baseline (5049.448 us; speedup 1.0000x reference)
//
#include <hip/hip_runtime.h>
#include <hip/hip_bf16.h>
#include <hip/hip_fp16.h>

#define EMB 300
#define NHID 600
#define NLAYERS 5
#define NG 4096
#define NCOMBO 18
#define SELFCB 12    // a0=4 (self-loop), a1=0 -> 4*3+0
#define HS 304       // padded byte stride of fp8 node-state rows
#define KP1 320      // Kpad for K=300 (EMB)
#define KP2 640      // Kpad for K=600 (NHID)
#define SCB 2048     // scan elems per block

__device__ __forceinline__ void atomAddF(float* p, float v) { unsafeAtomicAdd(p, v); }

// ---- fp8 e4m3 (OCP) codecs: manual + hardware-packed where available ----
__device__ __forceinline__ unsigned char enc8(float x) {
    unsigned xb = __float_as_uint(x);
    unsigned s = (xb >> 24) & 0x80u;
    float a = __uint_as_float(xb & 0x7FFFFFFFu);
    if (!(a < 448.f)) return (unsigned char)(s | 0x7E);
    if (a < 0.0009765625f) return (unsigned char)s;
    if (a < 0.015625f) {
        int m = (int)(a * 512.f + 0.5f);
        if (m > 7) return (unsigned char)(s | 0x08);
        return (unsigned char)(s | (unsigned)m);
    }
    unsigned u = __float_as_uint(a) + 0x80000u;
    int e = (int)(u >> 23) - 127;
    if (e > 8) return (unsigned char)(s | 0x7E);
    unsigned m = (u >> 20) & 7u;
    return (unsigned char)(s | ((unsigned)(e + 7) << 3) | m);
}
__device__ __forceinline__ float dec8(unsigned char c) {
    unsigned s = c & 0x80u, e = (c >> 3) & 0xFu, m = c & 7u;
    float v = (e == 0) ? (float)m * 0.001953125f
                       : __uint_as_float(((e + 120u) << 23) | (m << 20));
    return s ? -v : v;
}

typedef float fx2 __attribute__((ext_vector_type(2)));

#if defined(__has_builtin)
#if __has_builtin(__builtin_amdgcn_cvt_pk_f32_fp8) && __has_builtin(__builtin_amdgcn_cvt_pk_fp8_f32)
#define HWFP8 1
#endif
#endif

__device__ __forceinline__ void dec4(unsigned w, float& v0, float& v1, float& v2, float& v3) {
#ifdef HWFP8
    fx2 lo = __builtin_amdgcn_cvt_pk_f32_fp8((int)w, false);
    fx2 hi = __builtin_amdgcn_cvt_pk_f32_fp8((int)w, true);
    v0 = lo.x; v1 = lo.y; v2 = hi.x; v3 = hi.y;
#else
    v0 = dec8(w & 0xff); v1 = dec8((w >> 8) & 0xff);
    v2 = dec8((w >> 16) & 0xff); v3 = dec8((w >> 24) & 0xff);
#endif
}
__device__ __forceinline__ unsigned enc4(float v0, float v1, float v2, float v3) {
#ifdef HWFP8
    int w = __builtin_amdgcn_cvt_pk_fp8_f32(v0, v1, 0, false);
    w = __builtin_amdgcn_cvt_pk_fp8_f32(v2, v3, w, true);
    return (unsigned)w;
#else
    return (unsigned)enc8(v0) | ((unsigned)enc8(v1) << 8)
         | ((unsigned)enc8(v2) << 16) | ((unsigned)enc8(v3) << 24);
#endif
}
__device__ __forceinline__ unsigned char enc1(float v) {
#ifdef HWFP8
    return (unsigned char)(__builtin_amdgcn_cvt_pk_fp8_f32(v, 0.f, 0, false) & 0xff);
#else
    return enc8(v);
#endif
}
__device__ __forceinline__ float dec1(unsigned char c) {
#ifdef HWFP8
    fx2 lo = __builtin_amdgcn_cvt_pk_f32_fp8((int)(unsigned)c, false);
    return lo.x;
#else
    return dec8(c);
#endif
}

typedef _Float16 f16t;
typedef _Float16 f16x8 __attribute__((ext_vector_type(8)));
typedef float f32x4 __attribute__((ext_vector_type(4)));

__device__ __forceinline__ void stF(float* p, float v) { *p = v; }
__device__ __forceinline__ void stF(__half* p, float v) { *p = __float2half(v); }

// ---------------- tiny utility kernels ----------------

__global__ void zero_f32_v6(float* __restrict__ p, long n) {
    long s = (long)gridDim.x * blockDim.x;
    for (long i = blockIdx.x * (long)blockDim.x + threadIdx.x; i < n; i += s) p[i] = 0.f;
}
__global__ void zero_i32_v8(int* __restrict__ p, int n) {
    int s = gridDim.x * blockDim.x;
    for (int i = blockIdx.x * blockDim.x + threadIdx.x; i < n; i += s) p[i] = 0;
}
__global__ void copy_i32_v8(const int* __restrict__ a, int* __restrict__ b, int n) {
    int s = gridDim.x * blockDim.x;
    for (int i = blockIdx.x * blockDim.x + threadIdx.x; i < n; i += s) b[i] = a[i];
}
__global__ void labels_v6(float* __restrict__ out, int n) {
    int i = blockIdx.x * blockDim.x + threadIdx.x;
    if (i < n) out[i] = (float)i;
}

// ---------------- CSR build ----------------

__global__ void hist_dst_v8(const int* __restrict__ ei, int* __restrict__ deg, int E) {
    int s = gridDim.x * blockDim.x;
    for (int e = blockIdx.x * blockDim.x + threadIdx.x; e < E; e += s)
        atomicAdd(&deg[ei[E + e]], 1);
}
__global__ void hist_b_v8(const int* __restrict__ b, int* __restrict__ deg, int n) {
    int s = gridDim.x * blockDim.x;
    for (int i = blockIdx.x * blockDim.x + threadIdx.x; i < n; i += s)
        atomicAdd(&deg[b[i]], 1);
}

__global__ __launch_bounds__(256) void scan_excl_v8(const int* __restrict__ in,
                                                    int* __restrict__ out, int n) {
    __shared__ int part[256];
    int span = (n + 255) / 256;
    int t = threadIdx.x;
    int s0 = t * span, s1 = min(s0 + span, n);
    int sum = 0;
    for (int i = s0; i < s1; ++i) sum += in[i];
    part[t] = sum;
    __syncthreads();
    int v = sum;
    for (int off = 1; off < 256; off <<= 1) {
        int u = (t >= off) ? part[t - off] : 0;
        __syncthreads();
        part[t] += u;
        __syncthreads();
    }
    int run = part[t] - v;
    for (int i = s0; i < s1; ++i) { out[i] = run; run += in[i]; }
    if (t == 255) out[n] = run;
}

__global__ __launch_bounds__(256) void scan_bsum_v10(const int* __restrict__ in,
                                                     int* __restrict__ bsum, int n) {
    __shared__ int red[256];
    int b = blockIdx.x, t = threadIdx.x;
    int base = b * SCB + t * 8;
    int s = 0;
#pragma unroll
    for (int i = 0; i < 8; ++i) { int idx = base + i; if (idx < n) s += in[idx]; }
    red[t] = s; __syncthreads();
#pragma unroll
    for (int o = 128; o > 0; o >>= 1) {
        if (t < o) red[t] += red[t + o];
        __syncthreads();
    }
    if (t == 0) bsum[b] = red[0];
}

__global__ __launch_bounds__(256) void scan_top_v10(int* __restrict__ bsum, int nb,
                                                    int* __restrict__ total_out) {
    __shared__ int part[256];
    int t = threadIdx.x;
    int v = (t < nb) ? bsum[t] : 0;
    part[t] = v;
    __syncthreads();
    for (int o = 1; o < 256; o <<= 1) {
        int u = (t >= o) ? part[t - o] : 0;
        __syncthreads();
        part[t] += u;
        __syncthreads();
    }
    if (t < nb) bsum[t] = part[t] - v;
    if (t == 255) *total_out = part[255];
}

__global__ __launch_bounds__(256) void scan_fill_v10(const int* __restrict__ in,
                                                     const int* __restrict__ bsum,
                                                     int* __restrict__ out, int n) {
    __shared__ int red[256];
    int b = blockIdx.x, t = threadIdx.x;
    int base = b * SCB + t * 8;
    int v[8]; int s = 0;
#pragma unroll
    for (int i = 0; i < 8; ++i) { int idx = base + i; v[i] = (idx < n) ? in[idx] : 0; s += v[i]; }
    red[t] = s;
    __syncthreads();
    int self = s;
    for (int o = 1; o < 256; o <<= 1) {
        int u = (t >= o) ? red[t - o] : 0;
        __syncthreads();
        red[t] += u;
        __syncthreads();
    }
    int run = bsum[b] + red[t] - self;
#pragma unroll
    for (int i = 0; i < 8; ++i) { int idx = base + i; if (idx < n) out[idx] = run; run += v[i]; }
}

__global__ void fill_csr_v8(const int* __restrict__ ei, const int* __restrict__ ea,
                            int* __restrict__ cursor, int* __restrict__ csrc,
                            int* __restrict__ ccombo, int E) {
    int s = gridDim.x * blockDim.x;
    for (int e = blockIdx.x * blockDim.x + threadIdx.x; e < E; e += s) {
        int dst = ei[E + e];
        int pos = atomicAdd(&cursor[dst], 1);
        csrc[pos] = ei[e];
        ccombo[pos] = ea[2 * e] * 3 + ea[2 * e + 1];
    }
}

__global__ void tbl_v8(const float* __restrict__ ee1, const float* __restrict__ ee2,
                       float* __restrict__ tbl) {
    int idx = blockIdx.x * blockDim.x + threadIdx.x;
    if (idx >= NLAYERS * NCOMBO * EMB) return;
    int j = idx % EMB;
    int cb = (idx / EMB) % NCOMBO;
    int l = idx / (EMB * NCOMBO);
    tbl[idx] = ee1[(l * 6 + cb / 3) * EMB + j] + ee2[(l * 3 + cb % 3) * EMB + j];
}

// f16 weight transpose+pad (projection head)
__global__ void wtrans_v9(const float* __restrict__ W, f16t* __restrict__ Wt,
                          int K, int N, int Kpad) {
    int idx = blockIdx.x * blockDim.x + threadIdx.x;
    if (idx >= N * Kpad) return;
    int n = idx / Kpad, k = idx - n * Kpad;
    Wt[idx] = (k < K) ? (f16t)W[(size_t)k * N + n] : (f16t)0.f;
}

// fp8 weight transpose+pad (MLP)
__global__ void wtrans8_v13(const float* __restrict__ W, unsigned char* __restrict__ Wt,
                            int K, int N, int Kpad) {
    int idx = blockIdx.x * blockDim.x + threadIdx.x;
    if (idx >= N * Kpad) return;
    int n = idx / Kpad, k = idx - n * Kpad;
    Wt[idx] = (k < K) ? enc8(W[(size_t)k * N + n]) : 0;
}

// ---------------- node init (dword stores, zeroes pads) ----------------

__global__ void init_h_v11(const int* __restrict__ x, const float* __restrict__ ae1,
                           const float* __restrict__ ae2, unsigned char* __restrict__ h,
                           int N) {
    int s = gridDim.x * blockDim.x;
    int total = N * (HS / 4);
    for (int idx = blockIdx.x * blockDim.x + threadIdx.x; idx < total; idx += s) {
        int i = idx / (HS / 4), d = idx - i * (HS / 4);
        int j = d * 4;
        int x0 = x[2 * i] * EMB, x1 = x[2 * i + 1] * EMB;
        unsigned out = 0;
#pragma unroll
        for (int t = 0; t < 4; ++t) {
            int jj = j + t;
            unsigned char b = 0;
            if (jj < EMB) b = enc8(ae1[x0 + jj] + ae2[x1 + jj]);
            out |= (unsigned)b << (8 * t);
        }
        *(unsigned*)(h + (size_t)i * HS + j) = out;
    }
}

// ---------------- CSR gather + fused BN/ReLU; 2 edges in flight (verified v18) ----------------
template<bool BN>
__global__ __launch_bounds__(256)
void gather_v18(const unsigned char* __restrict__ h, const int* __restrict__ rp,
                const int* __restrict__ csrc, const int* __restrict__ ccombo,
                const float* __restrict__ tbl, const float* __restrict__ scl,
                const float* __restrict__ sft, unsigned char* __restrict__ aggc,
                int c0, int c1) {
    __shared__ float T[NCOMBO * EMB];
    __shared__ float SC[EMB + 4];
    __shared__ float SF[EMB + 4];
    for (int t = threadIdx.x; t < NCOMBO * EMB; t += 256) T[t] = tbl[t];
    if (BN) {
        for (int t = threadIdx.x; t < EMB; t += 256) { SC[t] = scl[t]; SF[t] = sft[t]; }
    }
    __syncthreads();
    int wid = (blockIdx.x * blockDim.x + threadIdx.x) >> 6;
    int lane = threadIdx.x & 63;
    int nw = (gridDim.x * blockDim.x) >> 6;
    const int jt = 256 + lane;
    float4 sc4, sf4; float sct = 1.f, sff = 0.f;
    if (BN) {
        sc4 = *(const float4*)&SC[lane << 2];
        sf4 = *(const float4*)&SF[lane << 2];
        if (lane < 44) { sct = SC[jt]; sff = SF[jt]; }
    }
#define BNAPP(val, sc, sf) { if (BN) (val) = fmaxf(fmaf((val), (sc), (sf)), 0.f); }
    for (int i = c0 + wid; i < c1; i += nw) {
        int p0 = rp[i], p1 = rp[i + 1];
        float a0, a1, a2, a3, at = 0.f;
        {
            const unsigned char* hr = h + (size_t)i * HS;
            unsigned w = *(const unsigned*)(hr + (lane << 2));
            float4 t4 = *(const float4*)&T[SELFCB * EMB + (lane << 2)];
            float v0, v1, v2, v3;
            dec4(w, v0, v1, v2, v3);
            BNAPP(v0, sc4.x, sf4.x); BNAPP(v1, sc4.y, sf4.y);
            BNAPP(v2, sc4.z, sf4.z); BNAPP(v3, sc4.w, sf4.w);
            a0 = v0 + t4.x; a1 = v1 + t4.y; a2 = v2 + t4.z; a3 = v3 + t4.w;
            if (lane < 44) {
                float vt = dec1(hr[jt]);
                BNAPP(vt, sct, sff);
                at = vt + T[SELFCB * EMB + jt];
            }
        }
        int p = p0;
        for (; p + 1 < p1; p += 2) {
            int sA = csrc[p],     cbA = ccombo[p];
            int sB = csrc[p + 1], cbB = ccombo[p + 1];
            const unsigned char* hA = h + (size_t)sA * HS;
            const unsigned char* hB = h + (size_t)sB * HS;
            unsigned wA = *(const unsigned*)(hA + (lane << 2));
            unsigned wB = *(const unsigned*)(hB + (lane << 2));
            float tA = 0.f, tB = 0.f;
            if (lane < 44) { tA = dec1(hA[jt]); tB = dec1(hB[jt]); }
            {
                float4 t4 = *(const float4*)&T[cbA * EMB + (lane << 2)];
                float v0, v1, v2, v3;
                dec4(wA, v0, v1, v2, v3);
                BNAPP(v0, sc4.x, sf4.x); BNAPP(v1, sc4.y, sf4.y);
                BNAPP(v2, sc4.z, sf4.z); BNAPP(v3, sc4.w, sf4.w);
                a0 += v0 + t4.x; a1 += v1 + t4.y; a2 += v2 + t4.z; a3 += v3 + t4.w;
                if (lane < 44) {
                    BNAPP(tA, sct, sff);
                    at += tA + T[cbA * EMB + jt];
                }
            }
            {
                float4 t4 = *(const float4*)&T[cbB * EMB + (lane << 2)];
                float v0, v1, v2, v3;
                dec4(wB, v0, v1, v2, v3);
                BNAPP(v0, sc4.x, sf4.x); BNAPP(v1, sc4.y, sf4.y);
                BNAPP(v2, sc4.z, sf4.z); BNAPP(v3, sc4.w, sf4.w);
                a0 += v0 + t4.x; a1 += v1 + t4.y; a2 += v2 + t4.z; a3 += v3 + t4.w;
                if (lane < 44) {
                    BNAPP(tB, sct, sff);
                    at += tB + T[cbB * EMB + jt];
                }
            }
        }
        if (p < p1) {
            int sA = csrc[p], cbA = ccombo[p];
            const unsigned char* hA = h + (size_t)sA * HS;
            unsigned wA = *(const unsigned*)(hA + (lane << 2));
            float4 t4 = *(const float4*)&T[cbA * EMB + (lane << 2)];
            float v0, v1, v2, v3;
            dec4(wA, v0, v1, v2, v3);
            BNAPP(v0, sc4.x, sf4.x); BNAPP(v1, sc4.y, sf4.y);
            BNAPP(v2, sc4.z, sf4.z); BNAPP(v3, sc4.w, sf4.w);
            a0 += v0 + t4.x; a1 += v1 + t4.y; a2 += v2 + t4.z; a3 += v3 + t4.w;
            if (lane < 44) {
                float vt = dec1(hA[jt]);
                BNAPP(vt, sct, sff);
                at += vt + T[cbA * EMB + jt];
            }
        }
        unsigned char* out = aggc + (size_t)(i - c0) * KP1;
        *(unsigned*)(out + (lane << 2)) = enc4(a0, a1, a2, a3);
        if (lane < 44) out[jt] = enc1(at);
    }
#undef BNAPP
}

// ---------------- FUSED fp8 MLP: h = (relu(agg@W1+b1))@W2 + b2, z in LDS ----------------
// agg [M][KP1] fp8; W1t [600][KP1] fp8; W2t [300][KP2] fp8; H [M][ldh] fp8.
// 64 M-rows/block, 256 threads (4 waves x (64rows x 32cols)), acc[4][2].
__global__ __launch_bounds__(256)
void fused_mlp_v19(const unsigned char* __restrict__ A,
                   const unsigned char* __restrict__ W1t, const float* __restrict__ b1,
                   const unsigned char* __restrict__ W2t, const float* __restrict__ b2,
                   unsigned char* __restrict__ H, int ldh, int M,
                   float* __restrict__ sums)
{
    __shared__ char smem[55296];
    char* Ast = smem;              // [64][72]   = 4608 (phase1 A staging; phase2: Cl)
    char* Bst = smem + 4608;       // [128][72]  = 9216 (B staging; epilogue: Sred/Qred)
    char* zL  = smem + 13824;      // [64][648]  = 41472 (z tile, fp8)
    const int tid = threadIdx.x;
    const int lane = tid & 63;
    const int wgid = tid >> 6;     // 0..3
    const int wc = wgid << 5;      // 0,32,64,96
    const int row0 = blockIdx.x * 64;
    const int fr = lane & 15;
    const int kbase = (lane >> 4) << 3;
    const int rb = (lane >> 4) << 2;

    // ================= phase 1: z = relu(agg @ W1 + b1) -> zL =================
    for (int nc = 0; nc < 5; ++nc) {
        f32x4 acc[4][2] = {};
        for (int kt = 0; kt < 5; ++kt) {          // K = 320
            const int k0 = kt << 6;
            {   // stage A 64x64 (16B/thread)
                int r = tid >> 2, sg = (tid & 3) << 4;
                int4 v = {0, 0, 0, 0};
                int gr = row0 + r;
                if (gr < M) v = *(const int4*)(A + (size_t)gr * KP1 + k0 + sg);
                char* d = Ast + r * 72 + sg;
                *(long*)(d)     = ((const long*)&v)[0];
                *(long*)(d + 8) = ((const long*)&v)[1];
            }
            {   // stage B = W1 cols [nc*128..+128) x 64 (32B/thread)
                int c = tid >> 1, sg = (tid & 1) << 5;
                int gc = nc * 128 + c;
                int4 v0 = {0, 0, 0, 0}, v1 = {0, 0, 0, 0};
                if (gc < NHID) {
                    const unsigned char* src = W1t + (size_t)gc * KP1 + k0 + sg;
                    v0 = *(const int4*)src; v1 = *(const int4*)(src + 16);
                }
                char* d = Bst + c * 72 + sg;
                *(long*)(d)      = ((const long*)&v0)[0];
                *(long*)(d + 8)  = ((const long*)&v0)[1];
                *(long*)(d + 16) = ((const long*)&v1)[0];
                *(long*)(d + 24) = ((const long*)&v1)[1];
            }
            __syncthreads();
#pragma unroll
            for (int ks = 0; ks < 2; ++ks) {
                const int kg = kbase + ks * 32;
                long af[4], bf[2];
#pragma unroll
                for (int mi = 0; mi < 4; ++mi)
                    af[mi] = *(const long*)(Ast + (mi * 16 + fr) * 72 + kg);
#pragma unroll
                for (int ni = 0; ni < 2; ++ni)
                    bf[ni] = *(const long*)(Bst + (wc + ni * 16 + fr) * 72 + kg);
#pragma unroll
                for (int mi = 0; mi < 4; ++mi)
#pragma unroll
                    for (int ni = 0; ni < 2; ++ni)
                        acc[mi][ni] = __builtin_amdgcn_mfma_f32_16x16x32_fp8_fp8(
                            af[mi], bf[ni], acc[mi][ni], 0, 0, 0);
            }
            __syncthreads();
        }
        // epilogue: relu(+bias) -> zL chunk (byte writes; pads get 0)
#pragma unroll
        for (int ni = 0; ni < 2; ++ni) {
            const int zc = nc * 128 + wc + ni * 16 + fr;    // 0..639
            const float bv = (zc < NHID) ? b1[zc] : 0.f;
#pragma unroll
            for (int mi = 0; mi < 4; ++mi)
#pragma unroll
                for (int i = 0; i < 4; ++i) {
                    const int rloc = mi * 16 + rb + i;
                    float v = fmaxf(acc[mi][ni][i] + bv, 0.f);
                    zL[rloc * 648 + zc] = (char)enc1(v);
                }
        }
        __syncthreads();
    }

    // ================= phase 2: h = z @ W2 + b2 (z from zL) =================
    char* Cl = Ast;                         // [64][72]
    float* Sred = (float*)Bst;              // [128][4]
    float* Qred = (float*)(Bst + 2048);     // [128][4]
    for (int nc = 0; nc < 3; ++nc) {
        const int col0 = nc * 128;
        f32x4 acc[4][2] = {};
        for (int kt = 0; kt < 10; ++kt) {         // K = 640
            const int k0 = kt << 6;
            {   // stage B = W2 cols [col0..+128) x 64
                int c = tid >> 1, sg = (tid & 1) << 5;
                int gc = col0 + c;
                int4 v0 = {0, 0, 0, 0}, v1 = {0, 0, 0, 0};
                if (gc < EMB) {
                    const unsigned char* src = W2t + (size_t)gc * KP2 + k0 + sg;
                    v0 = *(const int4*)src; v1 = *(const int4*)(src + 16);
                }
                char* d = Bst + c * 72 + sg;
                *(long*)(d)      = ((const long*)&v0)[0];
                *(long*)(d + 8)  = ((const long*)&v0)[1];
                *(long*)(d + 16) = ((const long*)&v1)[0];
                *(long*)(d + 24) = ((const long*)&v1)[1];
            }
            __syncthreads();
#pragma unroll
            for (int ks = 0; ks < 2; ++ks) {
                const int kgz = k0 + kbase + ks * 32;
                const int kgb = kbase + ks * 32;
                long af[4], bf[2];
#pragma unroll
                for (int mi = 0; mi < 4; ++mi)
                    af[mi] = *(const long*)(zL + (mi * 16 + fr) * 648 + kgz);
#pragma unroll
                for (int ni = 0; ni < 2; ++ni)
                    bf[ni] = *(const long*)(Bst + (wc + ni * 16 + fr) * 72 + kgb);
#pragma unroll
                for (int mi = 0; mi < 4; ++mi)
#pragma unroll
                    for (int ni = 0; ni < 2; ++ni)
                        acc[mi][ni] = __builtin_amdgcn_mfma_f32_16x16x32_fp8_fp8(
                            af[mi], bf[ni], acc[mi][ni], 0, 0, 0);
            }
            __syncthreads();
        }
        // ---- stats (pre-quantization values, guarded) into Bst scratch ----
#pragma unroll
        for (int ni = 0; ni < 2; ++ni) {
            const int cb = wc + ni * 16 + fr;          // 0..127
            const int c = col0 + cb;
            const float bv = (c < EMB) ? b2[c] : 0.f;
            float ls = 0.f, lq = 0.f;
#pragma unroll
            for (int mi = 0; mi < 4; ++mi)
#pragma unroll
                for (int i = 0; i < 4; ++i) {
                    const int rloc = mi * 16 + rb + i;
                    if (row0 + rloc < M && c < EMB) {
                        float v = acc[mi][ni][i] + bv;
                        ls += v; lq = fmaf(v, v, lq);
                    }
                }
            Sred[cb * 4 + (lane >> 4)] = ls;
            Qred[cb * 4 + (lane >> 4)] = lq;
        }
        __syncthreads();
        if (tid < 128) {
            int c = col0 + tid;
            if (c < EMB) {
                float s = Sred[tid * 4] + Sred[tid * 4 + 1]
                        + Sred[tid * 4 + 2] + Sred[tid * 4 + 3];
                float q = Qred[tid * 4] + Qred[tid * 4 + 1]
                        + Qred[tid * 4 + 2] + Qred[tid * 4 + 3];
                atomAddF(&sums[c], s);
                atomAddF(&sums[EMB + c], q);
            }
        }
        // ---- store h via Cl in two 64-col half-passes ----
        for (int hp = 0; hp < 2; ++hp) {
            __syncthreads();
            if ((wgid >> 1) == hp) {     // waves {0,1} -> half 0, {2,3} -> half 1
#pragma unroll
                for (int ni = 0; ni < 2; ++ni) {
                    const int lc = wc + ni * 16 + fr - hp * 64;   // 0..63
                    const int c = col0 + wc + ni * 16 + fr;
                    const float bv = (c < EMB) ? b2[c] : 0.f;
#pragma unroll
                    for (int mi = 0; mi < 4; ++mi)
#pragma unroll
                        for (int i = 0; i < 4; ++i) {
                            const int rloc = mi * 16 + rb + i;
                            float v = (c < EMB) ? (acc[mi][ni][i] + bv) : 0.f;
                            Cl[rloc * 72 + lc] = (char)enc1(v);
                        }
                }
            }
            __syncthreads();
            {   // coalesced copy 64x64 -> H
                int r = tid >> 2, sg = (tid & 3) << 4;
                int grow = row0 + r;
                int gcol = col0 + hp * 64 + sg;
                if (grow < M && gcol + 16 <= ldh) {
                    *(int4*)(H + (size_t)grow * ldh + gcol) = *(const int4*)(Cl + r * 72 + sg);
                }
            }
        }
        __syncthreads();
    }
}

// ---------------- F16 MFMA GEMM (projection head + logits; verified v12) ----------------
template<typename TO, int MODE>   // 1=+bias, 2=+bias+relu, 3=*scale+clamp
__global__ __launch_bounds__(256)
void fast_gemm_v12(const f16t* __restrict__ A, int lda,
                   const f16t* __restrict__ Bt, int ldb,
                   const float* __restrict__ bias, TO* __restrict__ C, int ldc,
                   int M, int N, int Kpad, float scale)
{
    __shared__ f16t Al[128][76];
    __shared__ f16t Bl[128][76];
    const int tid = threadIdx.x;
    const int lane = tid & 63;
    const int wid = tid >> 6;
    const int wr = (wid >> 1) << 6;
    const int wc = (wid & 1) << 6;
    const int row0 = blockIdx.y * 128;
    const int col0 = blockIdx.x * 128;
    f32x4 acc[4][4] = {};
    const int nkt = Kpad >> 6;
    const int sr = tid >> 1;
    const int skb = (tid & 1) << 5;

    for (int kt = 0; kt < nkt; ++kt) {
        const int k0 = kt << 6;
        {
            const int gr = row0 + sr;
            const f16t* src = A + (size_t)gr * lda + k0 + skb;
            f16x8 v0 = {}, v1 = {}, v2 = {}, v3 = {};
            if (gr < M) {
                v0 = *(const f16x8*)(src);
                v1 = *(const f16x8*)(src + 8);
                v2 = *(const f16x8*)(src + 16);
                v3 = *(const f16x8*)(src + 24);
            }
            *(f16x8*)&Al[sr][skb]      = v0;
            *(f16x8*)&Al[sr][skb + 8]  = v1;
            *(f16x8*)&Al[sr][skb + 16] = v2;
            *(f16x8*)&Al[sr][skb + 24] = v3;
        }
        {
            const int gc = col0 + sr;
            const f16t* src = Bt + (size_t)gc * ldb + k0 + skb;
            f16x8 v0 = {}, v1 = {}, v2 = {}, v3 = {};
            if (gc < N) {
                v0 = *(const f16x8*)(src);
                v1 = *(const f16x8*)(src + 8);
                v2 = *(const f16x8*)(src + 16);
                v3 = *(const f16x8*)(src + 24);
            }
            *(f16x8*)&Bl[sr][skb]      = v0;
            *(f16x8*)&Bl[sr][skb + 8]  = v1;
            *(f16x8*)&Bl[sr][skb + 16] = v2;
            *(f16x8*)&Bl[sr][skb + 24] = v3;
        }
        __syncthreads();
        const int fr = lane & 15;
        const int kbase = (lane >> 4) << 3;
#pragma unroll
        for (int ks = 0; ks < 2; ++ks) {
            const int kg8 = kbase + ks * 32;
            f16x8 af[4], bf[4];
#pragma unroll
            for (int mi = 0; mi < 4; ++mi)
                af[mi] = *(const f16x8*)&Al[wr + mi * 16 + fr][kg8];
#pragma unroll
            for (int ni = 0; ni < 4; ++ni)
                bf[ni] = *(const f16x8*)&Bl[wc + ni * 16 + fr][kg8];
#pragma unroll
            for (int mi = 0; mi < 4; ++mi)
#pragma unroll
                for (int ni = 0; ni < 4; ++ni)
                    acc[mi][ni] = __builtin_amdgcn_mfma_f32_16x16x32_f16(
                        af[mi], bf[ni], acc[mi][ni], 0, 0, 0);
        }
        __syncthreads();
    }
    const int fr = lane & 15;
    const int rb = (lane >> 4) << 2;
#pragma unroll
    for (int ni = 0; ni < 4; ++ni) {
        const int c = col0 + wc + ni * 16 + fr;
        if (c >= N) continue;
        const float bv = (MODE == 1 || MODE == 2) ? bias[c] : 0.f;
#pragma unroll
        for (int mi = 0; mi < 4; ++mi) {
#pragma unroll
            for (int i = 0; i < 4; ++i) {
                const int r = row0 + wr + mi * 16 + rb + i;
                if (r >= M) continue;
                float v = acc[mi][ni][i];
                if (MODE == 1 || MODE == 2) v += bv;
                if (MODE == 2) v = fmaxf(v, 0.f);
                v *= scale;
                if (MODE == 3) v = fmaxf(-26.f, fminf(26.f, v));
                stF(&C[(size_t)r * ldc + c], v);
            }
        }
    }
}

// ---------------- BN finalize ----------------

__global__ void bn_finalize_v6(const float* __restrict__ sums,
                               const float* __restrict__ gamma, const float* __restrict__ beta,
                               float* __restrict__ scl, float* __restrict__ sft, float inv_n) {
    int j = threadIdx.x;
    if (j < EMB) {
        float m = sums[j] * inv_n;
        float var = sums[EMB + j] * inv_n - m * m;
        float sc = gamma[j] * rsqrtf(var + 1e-5f);
        scl[j] = sc;
        sft[j] = beta[j] - m * sc;
    }
}

// ---------------- pooling (segment mean + final-layer BN affine, exact) ----------------

__global__ __launch_bounds__(256) void pool_seg_v11(const unsigned char* __restrict__ h,
                                                    const int* __restrict__ gptr,
                                                    const float* __restrict__ scl,
                                                    const float* __restrict__ sft,
                                                    __half* __restrict__ poolh) {
    int g = blockIdx.x;
    int s0 = gptr[g], s1 = gptr[g + 1];
    float inv = (s1 > s0) ? 1.f / (float)(s1 - s0) : 0.f;
    for (int j = threadIdx.x; j < EMB; j += 256) {
        float s = 0.f;
        for (int r = s0; r < s1; ++r) s += dec1(h[(size_t)r * HS + j]);
        float mv = (s1 > s0) ? fmaf(s * inv, scl[j], sft[j]) : 0.f;
        poolh[(size_t)g * KP1 + j] = __float2half(mv);
    }
}

// ---------------- row normalize -> f16 padded row ----------------

__global__ __launch_bounds__(256) void rownorm_f16_v12(const float* __restrict__ f,
                                                       f16t* __restrict__ fh) {
    __shared__ float red[256];
    __shared__ float inv;
    int r = blockIdx.x, tid = threadIdx.x;
    const float* row = f + (size_t)r * EMB;
    float s = 0.f;
    for (int j = tid; j < EMB; j += 256) { float v = row[j]; s = fmaf(v, v, s); }
    red[tid] = s;
    __syncthreads();
#pragma unroll
    for (int o = 128; o > 0; o >>= 1) {
        if (tid < o) red[tid] += red[tid + o];
        __syncthreads();
    }
    if (tid == 0) inv = rsqrtf(fmaxf(red[0], 1e-30f));
    __syncthreads();
    float iv = inv;
    for (int j = tid; j < KP1; j += 256)
        fh[(size_t)r * KP1 + j] = (j < EMB) ? (f16t)(row[j] * iv) : (f16t)0.f;
}

// ---------------- host launcher ----------------

extern "C" void kernel_launch(void* const* d_in, const int* in_sizes, int n_in,
                              void* d_out, int out_size, void* d_ws, size_t ws_size,
                              hipStream_t stream) {
    const int N = in_sizes[0] / 2;
    const int E = in_sizes[1] / 2;

    const float* atom1 = (const float*)d_in[8];
    const float* atom2 = (const float*)d_in[9];
    const float* ee1   = (const float*)d_in[10];
    const float* ee2   = (const float*)d_in[11];
    const float* W1    = (const float*)d_in[12];
    const float* bm1   = (const float*)d_in[13];
    const float* W2    = (const float*)d_in[14];
    const float* bm2   = (const float*)d_in[15];
    const float* gamma = (const float*)d_in[16];
    const float* beta  = (const float*)d_in[17];
    const float* Wp1   = (const float*)d_in[18];
    const float* bp1   = (const float*)d_in[19];
    const float* Wp2   = (const float*)d_in[20];
    const float* bp2   = (const float*)d_in[21];

    float* ob = (float*)d_out;

    unsigned char* h0 = (unsigned char*)d_out;   // overlays logits region
    bool h0_fits = ((size_t)N * HS) <= ((size_t)NG * NG * 4 - 256);

    size_t off = 0;
    char* base = (char*)d_ws;
    auto take = [&](size_t bytes) -> char* {
        char* p = base + off;
        off += (bytes + 255) & ~(size_t)255;
        return p;
    };
    unsigned char* h1 = (unsigned char*)take((size_t)N * HS);
    float* fbuf   = (float*)take((size_t)NG * EMB * 4);
    f16t*  fh     = (f16t*)take((size_t)2 * NG * KP1 * 2);
    float* sums   = (float*)take(2 * EMB * 4);
    float* scl    = (float*)take((size_t)NLAYERS * EMB * 4);
    float* sft    = (float*)take((size_t)NLAYERS * EMB * 4);
    int*   deg    = (int*)take((size_t)N * 4);
    int*   rp     = (int*)take((size_t)(N + 1) * 4);
    int*   cursor = (int*)take((size_t)N * 4);
    int*   csrc   = (int*)take((size_t)E * 4);
    int*   ccombo = (int*)take((size_t)E * 4);
    int*   bsum   = (int*)take(256 * 4);
    int*   gdeg   = (int*)take((size_t)NG * 4);
    int*   gptr   = (int*)take((size_t)(NG + 1) * 4);
    float* tbl    = (float*)take((size_t)NLAYERS * NCOMBO * EMB * 4);
    unsigned char* W1t8 = (unsigned char*)take((size_t)NLAYERS * NHID * KP1);
    unsigned char* W2t8 = (unsigned char*)take((size_t)NLAYERS * EMB * KP2);
    f16t*  Wp1t   = (f16t*)take((size_t)EMB * KP1 * 2);
    f16t*  Wp2t   = (f16t*)take((size_t)EMB * KP1 * 2);
    __half* poolh = (__half*)take((size_t)NG * KP1 * 2);
    __half* p1h   = (__half*)take((size_t)NG * KP1 * 2);

    long CN = 0;
    if (h0_fits && ws_size > off + 1024) {
        CN = (long)((ws_size - off - 1024) / KP1);
        if (CN > N) CN = N;
    }
    if (CN < 1024) {
        zero_f32_v6<<<2048, 256, 0, stream>>>(ob, (long)NG * NG);
        labels_v6<<<(NG + 255) / 256, 256, 0, stream>>>(ob + (size_t)NG * NG, NG);
        return;
    }
    unsigned char* aggc = (unsigned char*)take((size_t)CN * KP1);

    tbl_v8<<<(NLAYERS * NCOMBO * EMB + 255) / 256, 256, 0, stream>>>(ee1, ee2, tbl);
    for (int l = 0; l < NLAYERS; ++l) {
        wtrans8_v13<<<(NHID * KP1 + 255) / 256, 256, 0, stream>>>(
            W1 + (size_t)l * EMB * NHID, W1t8 + (size_t)l * NHID * KP1, EMB, NHID, KP1);
        wtrans8_v13<<<(EMB * KP2 + 255) / 256, 256, 0, stream>>>(
            W2 + (size_t)l * NHID * EMB, W2t8 + (size_t)l * EMB * KP2, NHID, EMB, KP2);
    }
    wtrans_v9<<<(EMB * KP1 + 255) / 256, 256, 0, stream>>>(Wp1, Wp1t, EMB, EMB, KP1);
    wtrans_v9<<<(EMB * KP1 + 255) / 256, 256, 0, stream>>>(Wp2, Wp2t, EMB, EMB, KP1);
    zero_f32_v6<<<2048, 256, 0, stream>>>((float*)aggc, CN * (KP1 / 4));
    zero_f32_v6<<<1024, 256, 0, stream>>>((float*)poolh, (long)NG * (KP1 / 2));
    zero_f32_v6<<<1024, 256, 0, stream>>>((float*)p1h, (long)NG * (KP1 / 2));

    const int nb = (N + SCB - 1) / SCB;

    for (int enc = 0; enc < 2; ++enc) {
        const int* x  = (const int*)d_in[enc * 4 + 0];
        const int* ei = (const int*)d_in[enc * 4 + 1];
        const int* ea = (const int*)d_in[enc * 4 + 2];
        const int* bi = (const int*)d_in[enc * 4 + 3];

        zero_i32_v8<<<256, 256, 0, stream>>>(deg, N);
        hist_dst_v8<<<1024, 256, 0, stream>>>(ei, deg, E);
        scan_bsum_v10<<<nb, 256, 0, stream>>>(deg, bsum, N);
        scan_top_v10<<<1, 256, 0, stream>>>(bsum, nb, rp + N);
        scan_fill_v10<<<nb, 256, 0, stream>>>(deg, bsum, rp, N);
        copy_i32_v8<<<256, 256, 0, stream>>>(rp, cursor, N);
        fill_csr_v8<<<1024, 256, 0, stream>>>(ei, ea, cursor, csrc, ccombo, E);
        zero_i32_v8<<<64, 256, 0, stream>>>(gdeg, NG);
        hist_b_v8<<<1024, 256, 0, stream>>>(bi, gdeg, N);
        scan_excl_v8<<<1, 256, 0, stream>>>(gdeg, gptr, NG);

        unsigned char* hc = h0;
        unsigned char* hn = h1;
        init_h_v11<<<4096, 256, 0, stream>>>(x, atom1, atom2, hc, N);

        for (int l = 0; l < NLAYERS; ++l) {
            const unsigned char* W1l = W1t8 + (size_t)l * NHID * KP1;
            const unsigned char* W2l = W2t8 + (size_t)l * EMB * KP2;
            const float* tl = tbl + (size_t)l * NCOMBO * EMB;
            const float* scp = scl + (size_t)(l - 1) * EMB;
            const float* sfp = sft + (size_t)(l - 1) * EMB;

            zero_f32_v6<<<1, 1024, 0, stream>>>(sums, 2 * EMB);

            for (long c0 = 0; c0 < N; c0 += CN) {
                int m = (int)((N - c0 < CN) ? (N - c0) : CN);
                if (l == 0)
                    gather_v18<false><<<2048, 256, 0, stream>>>(
                        hc, rp, csrc, ccombo, tl, nullptr, nullptr,
                        aggc, (int)c0, (int)(c0 + m));
                else
                    gather_v18<true><<<2048, 256, 0, stream>>>(
                        hc, rp, csrc, ccombo, tl, scp, sfp,
                        aggc, (int)c0, (int)(c0 + m));
                int gy = (m + 63) / 64;
                fused_mlp_v19<<<gy, 256, 0, stream>>>(
                    aggc, W1l, bm1 + l * NHID, W2l, bm2 + l * EMB,
                    hn + (size_t)c0 * HS, HS, m, sums);
            }

            bn_finalize_v6<<<1, 320, 0, stream>>>(sums, gamma + l * EMB, beta + l * EMB,
                                                  scl + (size_t)l * EMB,
                                                  sft + (size_t)l * EMB, 1.f / (float)N);
            unsigned char* t = hc; hc = hn; hn = t;
        }
        // NLAYERS=5 (odd): final raw state in h1; h0 (d_out overlay) dead.

        pool_seg_v11<<<NG, 256, 0, stream>>>(hc, gptr,
                                             scl + (size_t)(NLAYERS - 1) * EMB,
                                             sft + (size_t)(NLAYERS - 1) * EMB, poolh);

        dim3 gp((EMB + 127) / 128, (NG + 127) / 128);
        fast_gemm_v12<__half, 2><<<gp, 256, 0, stream>>>(
            (const f16t*)poolh, KP1, Wp1t, KP1, bp1, p1h, KP1, NG, EMB, KP1, 1.f);
        fast_gemm_v12<float, 1><<<gp, 256, 0, stream>>>(
            (const f16t*)p1h, KP1, Wp2t, KP1, bp2, fbuf, EMB, NG, EMB, KP1, 1.f);
        rownorm_f16_v12<<<NG, 256, 0, stream>>>(fbuf, fh + (size_t)enc * NG * KP1);
    }

    // logits = (f0h @ f1h^T) * 25, clamped, f16 MFMA; then labels
    f16t* f0h = fh;
    f16t* f1h = fh + (size_t)NG * KP1;
    dim3 gl(NG / 128, NG / 128);
    fast_gemm_v12<float, 3><<<gl, 256, 0, stream>>>(
        f0h, KP1, f1h, KP1, nullptr, ob, NG, NG, NG, KP1, 25.f);
    labels_v6<<<(NG + 255) / 256, 256, 0, stream>>>(ob + (size_t)NG * NG, NG);
}

// Round 21
// 4244.925 us; speedup vs baseline: 1.1895x; 1.1895x over previous
//
#include <hip/hip_runtime.h>
#include <hip/hip_bf16.h>
#include <hip/hip_fp16.h>

#define EMB 300
#define NHID 600
#define NLAYERS 5
#define NG 4096
#define NCOMBO 18
#define SELFCB 12    // a0=4 (self-loop), a1=0 -> 4*3+0
#define HS 304       // padded byte stride of fp8 node-state rows
#define KP1 320      // Kpad for K=300 (EMB)
#define KP2 640      // Kpad for K=600 (NHID)
#define SCB 2048     // scan elems per block

__device__ __forceinline__ void atomAddF(float* p, float v) { unsafeAtomicAdd(p, v); }

// ---- fp8 e4m3 (OCP) codecs: manual + hardware-packed where available ----
__device__ __forceinline__ unsigned char enc8(float x) {
    unsigned xb = __float_as_uint(x);
    unsigned s = (xb >> 24) & 0x80u;
    float a = __uint_as_float(xb & 0x7FFFFFFFu);
    if (!(a < 448.f)) return (unsigned char)(s | 0x7E);
    if (a < 0.0009765625f) return (unsigned char)s;
    if (a < 0.015625f) {
        int m = (int)(a * 512.f + 0.5f);
        if (m > 7) return (unsigned char)(s | 0x08);
        return (unsigned char)(s | (unsigned)m);
    }
    unsigned u = __float_as_uint(a) + 0x80000u;
    int e = (int)(u >> 23) - 127;
    if (e > 8) return (unsigned char)(s | 0x7E);
    unsigned m = (u >> 20) & 7u;
    return (unsigned char)(s | ((unsigned)(e + 7) << 3) | m);
}
__device__ __forceinline__ float dec8(unsigned char c) {
    unsigned s = c & 0x80u, e = (c >> 3) & 0xFu, m = c & 7u;
    float v = (e == 0) ? (float)m * 0.001953125f
                       : __uint_as_float(((e + 120u) << 23) | (m << 20));
    return s ? -v : v;
}

typedef float fx2 __attribute__((ext_vector_type(2)));

#if defined(__has_builtin)
#if __has_builtin(__builtin_amdgcn_cvt_pk_f32_fp8) && __has_builtin(__builtin_amdgcn_cvt_pk_fp8_f32)
#define HWFP8 1
#endif
#endif

__device__ __forceinline__ void dec4(unsigned w, float& v0, float& v1, float& v2, float& v3) {
#ifdef HWFP8
    fx2 lo = __builtin_amdgcn_cvt_pk_f32_fp8((int)w, false);
    fx2 hi = __builtin_amdgcn_cvt_pk_f32_fp8((int)w, true);
    v0 = lo.x; v1 = lo.y; v2 = hi.x; v3 = hi.y;
#else
    v0 = dec8(w & 0xff); v1 = dec8((w >> 8) & 0xff);
    v2 = dec8((w >> 16) & 0xff); v3 = dec8((w >> 24) & 0xff);
#endif
}
__device__ __forceinline__ unsigned enc4(float v0, float v1, float v2, float v3) {
#ifdef HWFP8
    int w = __builtin_amdgcn_cvt_pk_fp8_f32(v0, v1, 0, false);
    w = __builtin_amdgcn_cvt_pk_fp8_f32(v2, v3, w, true);
    return (unsigned)w;
#else
    return (unsigned)enc8(v0) | ((unsigned)enc8(v1) << 8)
         | ((unsigned)enc8(v2) << 16) | ((unsigned)enc8(v3) << 24);
#endif
}
__device__ __forceinline__ unsigned char enc1(float v) {
#ifdef HWFP8
    return (unsigned char)(__builtin_amdgcn_cvt_pk_fp8_f32(v, 0.f, 0, false) & 0xff);
#else
    return enc8(v);
#endif
}
__device__ __forceinline__ float dec1(unsigned char c) {
#ifdef HWFP8
    fx2 lo = __builtin_amdgcn_cvt_pk_f32_fp8((int)(unsigned)c, false);
    return lo.x;
#else
    return dec8(c);
#endif
}

typedef _Float16 f16t;
typedef _Float16 f16x8 __attribute__((ext_vector_type(8)));
typedef float f32x4 __attribute__((ext_vector_type(4)));

__device__ __forceinline__ void stF(float* p, float v) { *p = v; }
__device__ __forceinline__ void stF(__half* p, float v) { *p = __float2half(v); }

// ---------------- tiny utility kernels ----------------

__global__ void zero_f32_v6(float* __restrict__ p, long n) {
    long s = (long)gridDim.x * blockDim.x;
    for (long i = blockIdx.x * (long)blockDim.x + threadIdx.x; i < n; i += s) p[i] = 0.f;
}
__global__ void zero_i32_v8(int* __restrict__ p, int n) {
    int s = gridDim.x * blockDim.x;
    for (int i = blockIdx.x * blockDim.x + threadIdx.x; i < n; i += s) p[i] = 0;
}
__global__ void copy_i32_v8(const int* __restrict__ a, int* __restrict__ b, int n) {
    int s = gridDim.x * blockDim.x;
    for (int i = blockIdx.x * blockDim.x + threadIdx.x; i < n; i += s) b[i] = a[i];
}
__global__ void labels_v6(float* __restrict__ out, int n) {
    int i = blockIdx.x * blockDim.x + threadIdx.x;
    if (i < n) out[i] = (float)i;
}

// ---------------- CSR build ----------------

__global__ void hist_dst_v8(const int* __restrict__ ei, int* __restrict__ deg, int E) {
    int s = gridDim.x * blockDim.x;
    for (int e = blockIdx.x * blockDim.x + threadIdx.x; e < E; e += s)
        atomicAdd(&deg[ei[E + e]], 1);
}
__global__ void hist_b_v8(const int* __restrict__ b, int* __restrict__ deg, int n) {
    int s = gridDim.x * blockDim.x;
    for (int i = blockIdx.x * blockDim.x + threadIdx.x; i < n; i += s)
        atomicAdd(&deg[b[i]], 1);
}

__global__ __launch_bounds__(256) void scan_excl_v8(const int* __restrict__ in,
                                                    int* __restrict__ out, int n) {
    __shared__ int part[256];
    int span = (n + 255) / 256;
    int t = threadIdx.x;
    int s0 = t * span, s1 = min(s0 + span, n);
    int sum = 0;
    for (int i = s0; i < s1; ++i) sum += in[i];
    part[t] = sum;
    __syncthreads();
    int v = sum;
    for (int off = 1; off < 256; off <<= 1) {
        int u = (t >= off) ? part[t - off] : 0;
        __syncthreads();
        part[t] += u;
        __syncthreads();
    }
    int run = part[t] - v;
    for (int i = s0; i < s1; ++i) { out[i] = run; run += in[i]; }
    if (t == 255) out[n] = run;
}

__global__ __launch_bounds__(256) void scan_bsum_v10(const int* __restrict__ in,
                                                     int* __restrict__ bsum, int n) {
    __shared__ int red[256];
    int b = blockIdx.x, t = threadIdx.x;
    int base = b * SCB + t * 8;
    int s = 0;
#pragma unroll
    for (int i = 0; i < 8; ++i) { int idx = base + i; if (idx < n) s += in[idx]; }
    red[t] = s; __syncthreads();
#pragma unroll
    for (int o = 128; o > 0; o >>= 1) {
        if (t < o) red[t] += red[t + o];
        __syncthreads();
    }
    if (t == 0) bsum[b] = red[0];
}

__global__ __launch_bounds__(256) void scan_top_v10(int* __restrict__ bsum, int nb,
                                                    int* __restrict__ total_out) {
    __shared__ int part[256];
    int t = threadIdx.x;
    int v = (t < nb) ? bsum[t] : 0;
    part[t] = v;
    __syncthreads();
    for (int o = 1; o < 256; o <<= 1) {
        int u = (t >= o) ? part[t - o] : 0;
        __syncthreads();
        part[t] += u;
        __syncthreads();
    }
    if (t < nb) bsum[t] = part[t] - v;
    if (t == 255) *total_out = part[255];
}

__global__ __launch_bounds__(256) void scan_fill_v10(const int* __restrict__ in,
                                                     const int* __restrict__ bsum,
                                                     int* __restrict__ out, int n) {
    __shared__ int red[256];
    int b = blockIdx.x, t = threadIdx.x;
    int base = b * SCB + t * 8;
    int v[8]; int s = 0;
#pragma unroll
    for (int i = 0; i < 8; ++i) { int idx = base + i; v[i] = (idx < n) ? in[idx] : 0; s += v[i]; }
    red[t] = s;
    __syncthreads();
    int self = s;
    for (int o = 1; o < 256; o <<= 1) {
        int u = (t >= o) ? red[t - o] : 0;
        __syncthreads();
        red[t] += u;
        __syncthreads();
    }
    int run = bsum[b] + red[t] - self;
#pragma unroll
    for (int i = 0; i < 8; ++i) { int idx = base + i; if (idx < n) out[idx] = run; run += v[i]; }
}

__global__ void fill_csr_v8(const int* __restrict__ ei, const int* __restrict__ ea,
                            int* __restrict__ cursor, int* __restrict__ csrc,
                            int* __restrict__ ccombo, int E) {
    int s = gridDim.x * blockDim.x;
    for (int e = blockIdx.x * blockDim.x + threadIdx.x; e < E; e += s) {
        int dst = ei[E + e];
        int pos = atomicAdd(&cursor[dst], 1);
        csrc[pos] = ei[e];
        ccombo[pos] = ea[2 * e] * 3 + ea[2 * e + 1];
    }
}

__global__ void tbl_v8(const float* __restrict__ ee1, const float* __restrict__ ee2,
                       float* __restrict__ tbl) {
    int idx = blockIdx.x * blockDim.x + threadIdx.x;
    if (idx >= NLAYERS * NCOMBO * EMB) return;
    int j = idx % EMB;
    int cb = (idx / EMB) % NCOMBO;
    int l = idx / (EMB * NCOMBO);
    tbl[idx] = ee1[(l * 6 + cb / 3) * EMB + j] + ee2[(l * 3 + cb % 3) * EMB + j];
}

// f16 weight transpose+pad (projection head)
__global__ void wtrans_v9(const float* __restrict__ W, f16t* __restrict__ Wt,
                          int K, int N, int Kpad) {
    int idx = blockIdx.x * blockDim.x + threadIdx.x;
    if (idx >= N * Kpad) return;
    int n = idx / Kpad, k = idx - n * Kpad;
    Wt[idx] = (k < K) ? (f16t)W[(size_t)k * N + n] : (f16t)0.f;
}

// fp8 weight transpose+pad (MLP)
__global__ void wtrans8_v13(const float* __restrict__ W, unsigned char* __restrict__ Wt,
                            int K, int N, int Kpad) {
    int idx = blockIdx.x * blockDim.x + threadIdx.x;
    if (idx >= N * Kpad) return;
    int n = idx / Kpad, k = idx - n * Kpad;
    Wt[idx] = (k < K) ? enc8(W[(size_t)k * N + n]) : 0;
}

// ---------------- node init (dword stores, zeroes pads) ----------------

__global__ void init_h_v11(const int* __restrict__ x, const float* __restrict__ ae1,
                           const float* __restrict__ ae2, unsigned char* __restrict__ h,
                           int N) {
    int s = gridDim.x * blockDim.x;
    int total = N * (HS / 4);
    for (int idx = blockIdx.x * blockDim.x + threadIdx.x; idx < total; idx += s) {
        int i = idx / (HS / 4), d = idx - i * (HS / 4);
        int j = d * 4;
        int x0 = x[2 * i] * EMB, x1 = x[2 * i + 1] * EMB;
        unsigned out = 0;
#pragma unroll
        for (int t = 0; t < 4; ++t) {
            int jj = j + t;
            unsigned char b = 0;
            if (jj < EMB) b = enc8(ae1[x0 + jj] + ae2[x1 + jj]);
            out |= (unsigned)b << (8 * t);
        }
        *(unsigned*)(h + (size_t)i * HS + j) = out;
    }
}

// ---------------- CSR gather + fused BN/ReLU; 2 edges in flight (verified v18) ----------------
template<bool BN>
__global__ __launch_bounds__(256)
void gather_v18(const unsigned char* __restrict__ h, const int* __restrict__ rp,
                const int* __restrict__ csrc, const int* __restrict__ ccombo,
                const float* __restrict__ tbl, const float* __restrict__ scl,
                const float* __restrict__ sft, unsigned char* __restrict__ aggc,
                int c0, int c1) {
    __shared__ float T[NCOMBO * EMB];
    __shared__ float SC[EMB + 4];
    __shared__ float SF[EMB + 4];
    for (int t = threadIdx.x; t < NCOMBO * EMB; t += 256) T[t] = tbl[t];
    if (BN) {
        for (int t = threadIdx.x; t < EMB; t += 256) { SC[t] = scl[t]; SF[t] = sft[t]; }
    }
    __syncthreads();
    int wid = (blockIdx.x * blockDim.x + threadIdx.x) >> 6;
    int lane = threadIdx.x & 63;
    int nw = (gridDim.x * blockDim.x) >> 6;
    const int jt = 256 + lane;
    float4 sc4, sf4; float sct = 1.f, sff = 0.f;
    if (BN) {
        sc4 = *(const float4*)&SC[lane << 2];
        sf4 = *(const float4*)&SF[lane << 2];
        if (lane < 44) { sct = SC[jt]; sff = SF[jt]; }
    }
#define BNAPP(val, sc, sf) { if (BN) (val) = fmaxf(fmaf((val), (sc), (sf)), 0.f); }
    for (int i = c0 + wid; i < c1; i += nw) {
        int p0 = rp[i], p1 = rp[i + 1];
        float a0, a1, a2, a3, at = 0.f;
        {
            const unsigned char* hr = h + (size_t)i * HS;
            unsigned w = *(const unsigned*)(hr + (lane << 2));
            float4 t4 = *(const float4*)&T[SELFCB * EMB + (lane << 2)];
            float v0, v1, v2, v3;
            dec4(w, v0, v1, v2, v3);
            BNAPP(v0, sc4.x, sf4.x); BNAPP(v1, sc4.y, sf4.y);
            BNAPP(v2, sc4.z, sf4.z); BNAPP(v3, sc4.w, sf4.w);
            a0 = v0 + t4.x; a1 = v1 + t4.y; a2 = v2 + t4.z; a3 = v3 + t4.w;
            if (lane < 44) {
                float vt = dec1(hr[jt]);
                BNAPP(vt, sct, sff);
                at = vt + T[SELFCB * EMB + jt];
            }
        }
        int p = p0;
        for (; p + 1 < p1; p += 2) {
            int sA = csrc[p],     cbA = ccombo[p];
            int sB = csrc[p + 1], cbB = ccombo[p + 1];
            const unsigned char* hA = h + (size_t)sA * HS;
            const unsigned char* hB = h + (size_t)sB * HS;
            unsigned wA = *(const unsigned*)(hA + (lane << 2));
            unsigned wB = *(const unsigned*)(hB + (lane << 2));
            float tA = 0.f, tB = 0.f;
            if (lane < 44) { tA = dec1(hA[jt]); tB = dec1(hB[jt]); }
            {
                float4 t4 = *(const float4*)&T[cbA * EMB + (lane << 2)];
                float v0, v1, v2, v3;
                dec4(wA, v0, v1, v2, v3);
                BNAPP(v0, sc4.x, sf4.x); BNAPP(v1, sc4.y, sf4.y);
                BNAPP(v2, sc4.z, sf4.z); BNAPP(v3, sc4.w, sf4.w);
                a0 += v0 + t4.x; a1 += v1 + t4.y; a2 += v2 + t4.z; a3 += v3 + t4.w;
                if (lane < 44) {
                    BNAPP(tA, sct, sff);
                    at += tA + T[cbA * EMB + jt];
                }
            }
            {
                float4 t4 = *(const float4*)&T[cbB * EMB + (lane << 2)];
                float v0, v1, v2, v3;
                dec4(wB, v0, v1, v2, v3);
                BNAPP(v0, sc4.x, sf4.x); BNAPP(v1, sc4.y, sf4.y);
                BNAPP(v2, sc4.z, sf4.z); BNAPP(v3, sc4.w, sf4.w);
                a0 += v0 + t4.x; a1 += v1 + t4.y; a2 += v2 + t4.z; a3 += v3 + t4.w;
                if (lane < 44) {
                    BNAPP(tB, sct, sff);
                    at += tB + T[cbB * EMB + jt];
                }
            }
        }
        if (p < p1) {
            int sA = csrc[p], cbA = ccombo[p];
            const unsigned char* hA = h + (size_t)sA * HS;
            unsigned wA = *(const unsigned*)(hA + (lane << 2));
            float4 t4 = *(const float4*)&T[cbA * EMB + (lane << 2)];
            float v0, v1, v2, v3;
            dec4(wA, v0, v1, v2, v3);
            BNAPP(v0, sc4.x, sf4.x); BNAPP(v1, sc4.y, sf4.y);
            BNAPP(v2, sc4.z, sf4.z); BNAPP(v3, sc4.w, sf4.w);
            a0 += v0 + t4.x; a1 += v1 + t4.y; a2 += v2 + t4.z; a3 += v3 + t4.w;
            if (lane < 44) {
                float vt = dec1(hA[jt]);
                BNAPP(vt, sct, sff);
                at += vt + T[cbA * EMB + jt];
            }
        }
        unsigned char* out = aggc + (size_t)(i - c0) * KP1;
        *(unsigned*)(out + (lane << 2)) = enc4(a0, a1, a2, a3);
        if (lane < 44) out[jt] = enc1(at);
    }
#undef BNAPP
}

// ---------------- FP8 MFMA GEMM v20: v16 skeleton, TWO k-tiles per barrier pair ----------------
// A fp8 [M][lda]B, Bt fp8 [N][ldb]B, C fp8 [M][ldc]B. K=Kpad (mult of 64).
// MODE: 1=+bias, 2=+bias+relu. STATS: column sum/sumsq -> sums.
template<int MODE, bool STATS>
__global__ __launch_bounds__(256)
void fast_gemm8_v20(const unsigned char* __restrict__ A, int lda,
                    const unsigned char* __restrict__ Bt, int ldb,
                    const float* __restrict__ bias, unsigned char* __restrict__ C,
                    int ldc, int M, int N, int Kpad, int gx,
                    float* __restrict__ sums)
{
    __shared__ char smem[36864];   // A0,B0,A1,B1 regions of 9216 B each
    const int tid = threadIdx.x;
    const int lane = tid & 63;
    const int wid = tid >> 6;
    const int wr = (wid >> 1) << 6;
    const int wc = (wid & 1) << 6;

    const int nwg = gridDim.x;
    const int q = nwg >> 3, r = nwg & 7;
    const int xcd = blockIdx.x & 7, idx = blockIdx.x >> 3;
    const int swz = (xcd < r ? xcd * (q + 1) : r * (q + 1) + (xcd - r) * q) + idx;
    const int row0 = (swz / gx) * 128;
    const int col0 = (swz % gx) * 128;

    f32x4 acc[4][4] = {};
    const int nkt = Kpad >> 6;
    const int sr = tid >> 1;
    const int skb = (tid & 1) << 5;
    const int gr = row0 + sr;
    const int gc = col0 + sr;
    const int fr = lane & 15;
    const int kbase = (lane >> 4) << 3;

#define STAGE_TILE(buf, kt_) {                                                   \
        const int k0_ = (kt_) << 6;                                              \
        {                                                                        \
            const unsigned char* src = A + (size_t)gr * lda + k0_ + skb;         \
            int4 v0 = {0,0,0,0}, v1 = {0,0,0,0};                                 \
            if (gr < M) { v0 = *(const int4*)src; v1 = *(const int4*)(src + 16);}\
            char* dst = smem + (buf) * 18432 + sr * 72 + skb;                    \
            *(long*)(dst)      = ((const long*)&v0)[0];                          \
            *(long*)(dst + 8)  = ((const long*)&v0)[1];                          \
            *(long*)(dst + 16) = ((const long*)&v1)[0];                          \
            *(long*)(dst + 24) = ((const long*)&v1)[1];                          \
        }                                                                        \
        {                                                                        \
            const unsigned char* src = Bt + (size_t)gc * ldb + k0_ + skb;        \
            int4 v0 = {0,0,0,0}, v1 = {0,0,0,0};                                 \
            if (gc < N) { v0 = *(const int4*)src; v1 = *(const int4*)(src + 16);}\
            char* dst = smem + (buf) * 18432 + 9216 + sr * 72 + skb;             \
            *(long*)(dst)      = ((const long*)&v0)[0];                          \
            *(long*)(dst + 8)  = ((const long*)&v0)[1];                          \
            *(long*)(dst + 16) = ((const long*)&v1)[0];                          \
            *(long*)(dst + 24) = ((const long*)&v1)[1];                          \
        }                                                                        \
    }

#define MFMA_TILE(buf) {                                                         \
        const char* AlB = smem + (buf) * 18432;                                  \
        const char* BlB = AlB + 9216;                                            \
        _Pragma("unroll")                                                        \
        for (int ks = 0; ks < 2; ++ks) {                                         \
            const int kg = kbase + ks * 32;                                      \
            long af[4], bf[4];                                                   \
            _Pragma("unroll")                                                    \
            for (int mi = 0; mi < 4; ++mi)                                       \
                af[mi] = *(const long*)(AlB + (wr + mi * 16 + fr) * 72 + kg);    \
            _Pragma("unroll")                                                    \
            for (int ni = 0; ni < 4; ++ni)                                       \
                bf[ni] = *(const long*)(BlB + (wc + ni * 16 + fr) * 72 + kg);    \
            _Pragma("unroll")                                                    \
            for (int mi = 0; mi < 4; ++mi)                                       \
                _Pragma("unroll")                                                \
                for (int ni = 0; ni < 4; ++ni)                                   \
                    acc[mi][ni] = __builtin_amdgcn_mfma_f32_16x16x32_fp8_fp8(    \
                        af[mi], bf[ni], acc[mi][ni], 0, 0, 0);                   \
        }                                                                        \
    }

    int kt = 0;
    for (; kt + 1 < nkt; kt += 2) {
        STAGE_TILE(0, kt)
        STAGE_TILE(1, kt + 1)
        __syncthreads();
        MFMA_TILE(0)
        MFMA_TILE(1)
        __syncthreads();
    }
    if (kt < nkt) {
        STAGE_TILE(0, kt)
        __syncthreads();
        MFMA_TILE(0)
        __syncthreads();
    }
#undef STAGE_TILE
#undef MFMA_TILE

    // ---- epilogue: LDS dead; reuse as C tile [128][144] + stats ----
    char* Cl = smem;                          // 18432 B
    float* Sred = (float*)(smem + 18432);     // 4096 B
    float* Qred = (float*)(smem + 22528);     // 4096 B
    const int rb = (lane >> 4) << 2;
    const int slot = ((wid >> 1) << 2) | (lane >> 4);
#pragma unroll
    for (int ni = 0; ni < 4; ++ni) {
        const int cb = wc + ni * 16 + fr;
        const int c = col0 + cb;
        const float bv = (c < N) ? bias[c] : 0.f;
        float lsum = 0.f, lsq = 0.f;
#pragma unroll
        for (int mi = 0; mi < 4; ++mi) {
#pragma unroll
            for (int i = 0; i < 4; ++i) {
                const int rloc = wr + mi * 16 + rb + i;
                float v = acc[mi][ni][i] + bv;
                if (MODE == 2) v = fmaxf(v, 0.f);
                Cl[rloc * 144 + cb] = (char)enc1(v);
                if (STATS && (row0 + rloc) < M && c < N) {
                    lsum += v; lsq = fmaf(v, v, lsq);
                }
            }
        }
        if (STATS) { Sred[cb * 8 + slot] = lsum; Qred[cb * 8 + slot] = lsq; }
    }
    __syncthreads();
    {
        const int rloc = tid >> 1;
        const int half = (tid & 1) << 6;
        const int grow = row0 + rloc;
        if (grow < M) {
            int cmax = ldc - col0; if (cmax > 128) cmax = 128;
            unsigned char* dst = C + (size_t)grow * ldc + col0;
            const char* srcl = Cl + rloc * 144 + half;
#pragma unroll
            for (int qi = 0; qi < 4; ++qi) {
                if (half + qi * 16 + 16 <= cmax)
                    *(int4*)(dst + half + qi * 16) = *(const int4*)(srcl + qi * 16);
            }
        }
    }
    if (STATS) {
        if (tid < 128) {
            const int c = col0 + tid;
            if (c < N) {
                float s = 0.f, qq = 0.f;
#pragma unroll
                for (int k = 0; k < 8; ++k) { s += Sred[tid * 8 + k]; qq += Qred[tid * 8 + k]; }
                atomAddF(&sums[c], s);
                atomAddF(&sums[EMB + c], qq);
            }
        }
    }
}

// ---------------- F16 MFMA GEMM (projection head + logits; verified v12) ----------------
template<typename TO, int MODE>   // 1=+bias, 2=+bias+relu, 3=*scale+clamp
__global__ __launch_bounds__(256)
void fast_gemm_v12(const f16t* __restrict__ A, int lda,
                   const f16t* __restrict__ Bt, int ldb,
                   const float* __restrict__ bias, TO* __restrict__ C, int ldc,
                   int M, int N, int Kpad, float scale)
{
    __shared__ f16t Al[128][76];
    __shared__ f16t Bl[128][76];
    const int tid = threadIdx.x;
    const int lane = tid & 63;
    const int wid = tid >> 6;
    const int wr = (wid >> 1) << 6;
    const int wc = (wid & 1) << 6;
    const int row0 = blockIdx.y * 128;
    const int col0 = blockIdx.x * 128;
    f32x4 acc[4][4] = {};
    const int nkt = Kpad >> 6;
    const int sr = tid >> 1;
    const int skb = (tid & 1) << 5;

    for (int kt = 0; kt < nkt; ++kt) {
        const int k0 = kt << 6;
        {
            const int gr = row0 + sr;
            const f16t* src = A + (size_t)gr * lda + k0 + skb;
            f16x8 v0 = {}, v1 = {}, v2 = {}, v3 = {};
            if (gr < M) {
                v0 = *(const f16x8*)(src);
                v1 = *(const f16x8*)(src + 8);
                v2 = *(const f16x8*)(src + 16);
                v3 = *(const f16x8*)(src + 24);
            }
            *(f16x8*)&Al[sr][skb]      = v0;
            *(f16x8*)&Al[sr][skb + 8]  = v1;
            *(f16x8*)&Al[sr][skb + 16] = v2;
            *(f16x8*)&Al[sr][skb + 24] = v3;
        }
        {
            const int gc = col0 + sr;
            const f16t* src = Bt + (size_t)gc * ldb + k0 + skb;
            f16x8 v0 = {}, v1 = {}, v2 = {}, v3 = {};
            if (gc < N) {
                v0 = *(const f16x8*)(src);
                v1 = *(const f16x8*)(src + 8);
                v2 = *(const f16x8*)(src + 16);
                v3 = *(const f16x8*)(src + 24);
            }
            *(f16x8*)&Bl[sr][skb]      = v0;
            *(f16x8*)&Bl[sr][skb + 8]  = v1;
            *(f16x8*)&Bl[sr][skb + 16] = v2;
            *(f16x8*)&Bl[sr][skb + 24] = v3;
        }
        __syncthreads();
        const int fr = lane & 15;
        const int kbase = (lane >> 4) << 3;
#pragma unroll
        for (int ks = 0; ks < 2; ++ks) {
            const int kg8 = kbase + ks * 32;
            f16x8 af[4], bf[4];
#pragma unroll
            for (int mi = 0; mi < 4; ++mi)
                af[mi] = *(const f16x8*)&Al[wr + mi * 16 + fr][kg8];
#pragma unroll
            for (int ni = 0; ni < 4; ++ni)
                bf[ni] = *(const f16x8*)&Bl[wc + ni * 16 + fr][kg8];
#pragma unroll
            for (int mi = 0; mi < 4; ++mi)
#pragma unroll
                for (int ni = 0; ni < 4; ++ni)
                    acc[mi][ni] = __builtin_amdgcn_mfma_f32_16x16x32_f16(
                        af[mi], bf[ni], acc[mi][ni], 0, 0, 0);
        }
        __syncthreads();
    }
    const int fr = lane & 15;
    const int rb = (lane >> 4) << 2;
#pragma unroll
    for (int ni = 0; ni < 4; ++ni) {
        const int c = col0 + wc + ni * 16 + fr;
        if (c >= N) continue;
        const float bv = (MODE == 1 || MODE == 2) ? bias[c] : 0.f;
#pragma unroll
        for (int mi = 0; mi < 4; ++mi) {
#pragma unroll
            for (int i = 0; i < 4; ++i) {
                const int r = row0 + wr + mi * 16 + rb + i;
                if (r >= M) continue;
                float v = acc[mi][ni][i];
                if (MODE == 1 || MODE == 2) v += bv;
                if (MODE == 2) v = fmaxf(v, 0.f);
                v *= scale;
                if (MODE == 3) v = fmaxf(-26.f, fminf(26.f, v));
                stF(&C[(size_t)r * ldc + c], v);
            }
        }
    }
}

// ---------------- BN finalize ----------------

__global__ void bn_finalize_v6(const float* __restrict__ sums,
                               const float* __restrict__ gamma, const float* __restrict__ beta,
                               float* __restrict__ scl, float* __restrict__ sft, float inv_n) {
    int j = threadIdx.x;
    if (j < EMB) {
        float m = sums[j] * inv_n;
        float var = sums[EMB + j] * inv_n - m * m;
        float sc = gamma[j] * rsqrtf(var + 1e-5f);
        scl[j] = sc;
        sft[j] = beta[j] - m * sc;
    }
}

// ---------------- pooling (segment mean + final-layer BN affine, exact) ----------------

__global__ __launch_bounds__(256) void pool_seg_v11(const unsigned char* __restrict__ h,
                                                    const int* __restrict__ gptr,
                                                    const float* __restrict__ scl,
                                                    const float* __restrict__ sft,
                                                    __half* __restrict__ poolh) {
    int g = blockIdx.x;
    int s0 = gptr[g], s1 = gptr[g + 1];
    float inv = (s1 > s0) ? 1.f / (float)(s1 - s0) : 0.f;
    for (int j = threadIdx.x; j < EMB; j += 256) {
        float s = 0.f;
        for (int r = s0; r < s1; ++r) s += dec1(h[(size_t)r * HS + j]);
        float mv = (s1 > s0) ? fmaf(s * inv, scl[j], sft[j]) : 0.f;
        poolh[(size_t)g * KP1 + j] = __float2half(mv);
    }
}

// ---------------- row normalize -> f16 padded row ----------------

__global__ __launch_bounds__(256) void rownorm_f16_v12(const float* __restrict__ f,
                                                       f16t* __restrict__ fh) {
    __shared__ float red[256];
    __shared__ float inv;
    int r = blockIdx.x, tid = threadIdx.x;
    const float* row = f + (size_t)r * EMB;
    float s = 0.f;
    for (int j = tid; j < EMB; j += 256) { float v = row[j]; s = fmaf(v, v, s); }
    red[tid] = s;
    __syncthreads();
#pragma unroll
    for (int o = 128; o > 0; o >>= 1) {
        if (tid < o) red[tid] += red[tid + o];
        __syncthreads();
    }
    if (tid == 0) inv = rsqrtf(fmaxf(red[0], 1e-30f));
    __syncthreads();
    float iv = inv;
    for (int j = tid; j < KP1; j += 256)
        fh[(size_t)r * KP1 + j] = (j < EMB) ? (f16t)(row[j] * iv) : (f16t)0.f;
}

// ---------------- host launcher ----------------

extern "C" void kernel_launch(void* const* d_in, const int* in_sizes, int n_in,
                              void* d_out, int out_size, void* d_ws, size_t ws_size,
                              hipStream_t stream) {
    const int N = in_sizes[0] / 2;
    const int E = in_sizes[1] / 2;

    const float* atom1 = (const float*)d_in[8];
    const float* atom2 = (const float*)d_in[9];
    const float* ee1   = (const float*)d_in[10];
    const float* ee2   = (const float*)d_in[11];
    const float* W1    = (const float*)d_in[12];
    const float* bm1   = (const float*)d_in[13];
    const float* W2    = (const float*)d_in[14];
    const float* bm2   = (const float*)d_in[15];
    const float* gamma = (const float*)d_in[16];
    const float* beta  = (const float*)d_in[17];
    const float* Wp1   = (const float*)d_in[18];
    const float* bp1   = (const float*)d_in[19];
    const float* Wp2   = (const float*)d_in[20];
    const float* bp2   = (const float*)d_in[21];

    float* ob = (float*)d_out;

    unsigned char* h0 = (unsigned char*)d_out;   // overlays logits region
    bool h0_fits = ((size_t)N * HS) <= ((size_t)NG * NG * 4 - 256);

    size_t off = 0;
    char* base = (char*)d_ws;
    auto take = [&](size_t bytes) -> char* {
        char* p = base + off;
        off += (bytes + 255) & ~(size_t)255;
        return p;
    };
    unsigned char* h1 = (unsigned char*)take((size_t)N * HS);
    float* fbuf   = (float*)take((size_t)NG * EMB * 4);
    f16t*  fh     = (f16t*)take((size_t)2 * NG * KP1 * 2);
    float* sums   = (float*)take(2 * EMB * 4);
    float* scl    = (float*)take((size_t)NLAYERS * EMB * 4);
    float* sft    = (float*)take((size_t)NLAYERS * EMB * 4);
    int*   deg    = (int*)take((size_t)N * 4);
    int*   rp     = (int*)take((size_t)(N + 1) * 4);
    int*   cursor = (int*)take((size_t)N * 4);
    int*   csrc   = (int*)take((size_t)E * 4);
    int*   ccombo = (int*)take((size_t)E * 4);
    int*   bsum   = (int*)take(256 * 4);
    int*   gdeg   = (int*)take((size_t)NG * 4);
    int*   gptr   = (int*)take((size_t)(NG + 1) * 4);
    float* tbl    = (float*)take((size_t)NLAYERS * NCOMBO * EMB * 4);
    unsigned char* W1t8 = (unsigned char*)take((size_t)NLAYERS * NHID * KP1);
    unsigned char* W2t8 = (unsigned char*)take((size_t)NLAYERS * EMB * KP2);
    f16t*  Wp1t   = (f16t*)take((size_t)EMB * KP1 * 2);
    f16t*  Wp2t   = (f16t*)take((size_t)EMB * KP1 * 2);
    __half* poolh = (__half*)take((size_t)NG * KP1 * 2);
    __half* p1h   = (__half*)take((size_t)NG * KP1 * 2);

    long CN = 0;
    if (h0_fits && ws_size > off + 1024) {
        CN = (long)((ws_size - off - 1024) / (KP1 + KP2));
        if (CN > N) CN = N;
    }
    if (CN < 1024) {
        zero_f32_v6<<<2048, 256, 0, stream>>>(ob, (long)NG * NG);
        labels_v6<<<(NG + 255) / 256, 256, 0, stream>>>(ob + (size_t)NG * NG, NG);
        return;
    }
    unsigned char* aggc = (unsigned char*)take((size_t)CN * KP1);
    unsigned char* z    = (unsigned char*)take((size_t)CN * KP2);

    tbl_v8<<<(NLAYERS * NCOMBO * EMB + 255) / 256, 256, 0, stream>>>(ee1, ee2, tbl);
    for (int l = 0; l < NLAYERS; ++l) {
        wtrans8_v13<<<(NHID * KP1 + 255) / 256, 256, 0, stream>>>(
            W1 + (size_t)l * EMB * NHID, W1t8 + (size_t)l * NHID * KP1, EMB, NHID, KP1);
        wtrans8_v13<<<(EMB * KP2 + 255) / 256, 256, 0, stream>>>(
            W2 + (size_t)l * NHID * EMB, W2t8 + (size_t)l * EMB * KP2, NHID, EMB, KP2);
    }
    wtrans_v9<<<(EMB * KP1 + 255) / 256, 256, 0, stream>>>(Wp1, Wp1t, EMB, EMB, KP1);
    wtrans_v9<<<(EMB * KP1 + 255) / 256, 256, 0, stream>>>(Wp2, Wp2t, EMB, EMB, KP1);
    zero_f32_v6<<<2048, 256, 0, stream>>>((float*)aggc, CN * (KP1 / 4));
    zero_f32_v6<<<2048, 256, 0, stream>>>((float*)z, CN * (KP2 / 4));
    zero_f32_v6<<<1024, 256, 0, stream>>>((float*)poolh, (long)NG * (KP1 / 2));
    zero_f32_v6<<<1024, 256, 0, stream>>>((float*)p1h, (long)NG * (KP1 / 2));

    const int nb = (N + SCB - 1) / SCB;

    for (int enc = 0; enc < 2; ++enc) {
        const int* x  = (const int*)d_in[enc * 4 + 0];
        const int* ei = (const int*)d_in[enc * 4 + 1];
        const int* ea = (const int*)d_in[enc * 4 + 2];
        const int* bi = (const int*)d_in[enc * 4 + 3];

        zero_i32_v8<<<256, 256, 0, stream>>>(deg, N);
        hist_dst_v8<<<1024, 256, 0, stream>>>(ei, deg, E);
        scan_bsum_v10<<<nb, 256, 0, stream>>>(deg, bsum, N);
        scan_top_v10<<<1, 256, 0, stream>>>(bsum, nb, rp + N);
        scan_fill_v10<<<nb, 256, 0, stream>>>(deg, bsum, rp, N);
        copy_i32_v8<<<256, 256, 0, stream>>>(rp, cursor, N);
        fill_csr_v8<<<1024, 256, 0, stream>>>(ei, ea, cursor, csrc, ccombo, E);
        zero_i32_v8<<<64, 256, 0, stream>>>(gdeg, NG);
        hist_b_v8<<<1024, 256, 0, stream>>>(bi, gdeg, N);
        scan_excl_v8<<<1, 256, 0, stream>>>(gdeg, gptr, NG);

        unsigned char* hc = h0;
        unsigned char* hn = h1;
        init_h_v11<<<4096, 256, 0, stream>>>(x, atom1, atom2, hc, N);

        for (int l = 0; l < NLAYERS; ++l) {
            const unsigned char* W1l = W1t8 + (size_t)l * NHID * KP1;
            const unsigned char* W2l = W2t8 + (size_t)l * EMB * KP2;
            const float* tl = tbl + (size_t)l * NCOMBO * EMB;
            const float* scp = scl + (size_t)(l - 1) * EMB;
            const float* sfp = sft + (size_t)(l - 1) * EMB;

            zero_f32_v6<<<1, 1024, 0, stream>>>(sums, 2 * EMB);

            for (long c0 = 0; c0 < N; c0 += CN) {
                int m = (int)((N - c0 < CN) ? (N - c0) : CN);
                if (l == 0)
                    gather_v18<false><<<2048, 256, 0, stream>>>(
                        hc, rp, csrc, ccombo, tl, nullptr, nullptr,
                        aggc, (int)c0, (int)(c0 + m));
                else
                    gather_v18<true><<<2048, 256, 0, stream>>>(
                        hc, rp, csrc, ccombo, tl, scp, sfp,
                        aggc, (int)c0, (int)(c0 + m));
                int gx1 = (NHID + 127) / 128, gy1 = (m + 127) / 128;
                fast_gemm8_v20<2, false><<<gx1 * gy1, 256, 0, stream>>>(
                    aggc, KP1, W1l, KP1, bm1 + l * NHID,
                    z, KP2, m, NHID, KP1, gx1, nullptr);
                int gx2 = (EMB + 127) / 128;
                fast_gemm8_v20<1, true><<<gx2 * gy1, 256, 0, stream>>>(
                    z, KP2, W2l, KP2, bm2 + l * EMB,
                    hn + (size_t)c0 * HS, HS, m, EMB, KP2, gx2, sums);
            }

            bn_finalize_v6<<<1, 320, 0, stream>>>(sums, gamma + l * EMB, beta + l * EMB,
                                                  scl + (size_t)l * EMB,
                                                  sft + (size_t)l * EMB, 1.f / (float)N);
            unsigned char* t = hc; hc = hn; hn = t;
        }
        // NLAYERS=5 (odd): final raw state in h1; h0 (d_out overlay) dead.

        pool_seg_v11<<<NG, 256, 0, stream>>>(hc, gptr,
                                             scl + (size_t)(NLAYERS - 1) * EMB,
                                             sft + (size_t)(NLAYERS - 1) * EMB, poolh);

        dim3 gp((EMB + 127) / 128, (NG + 127) / 128);
        fast_gemm_v12<__half, 2><<<gp, 256, 0, stream>>>(
            (const f16t*)poolh, KP1, Wp1t, KP1, bp1, p1h, KP1, NG, EMB, KP1, 1.f);
        fast_gemm_v12<float, 1><<<gp, 256, 0, stream>>>(
            (const f16t*)p1h, KP1, Wp2t, KP1, bp2, fbuf, EMB, NG, EMB, KP1, 1.f);
        rownorm_f16_v12<<<NG, 256, 0, stream>>>(fbuf, fh + (size_t)enc * NG * KP1);
    }

    // logits = (f0h @ f1h^T) * 25, clamped, f16 MFMA; then labels
    f16t* f0h = fh;
    f16t* f1h = fh + (size_t)NG * KP1;
    dim3 gl(NG / 128, NG / 128);
    fast_gemm_v12<float, 3><<<gl, 256, 0, stream>>>(
        f0h, KP1, f1h, KP1, nullptr, ob, NG, NG, NG, KP1, 25.f);
    labels_v6<<<(NG + 255) / 256, 256, 0, stream>>>(ob + (size_t)NG * NG, NG);
}

// Round 22
// 4095.853 us; speedup vs baseline: 1.2328x; 1.0364x over previous
//
#include <hip/hip_runtime.h>
#include <hip/hip_bf16.h>
#include <hip/hip_fp16.h>

#define EMB 300
#define NHID 600
#define NLAYERS 5
#define NG 4096
#define NCOMBO 18
#define SELFCB 12    // a0=4 (self-loop), a1=0 -> 4*3+0
#define HS 304       // padded byte stride of fp8 node-state rows
#define KP1 320      // Kpad for K=300 (EMB)
#define KP2 640      // Kpad for K=600 (NHID)
#define SCB 2048     // scan elems per block

__device__ __forceinline__ void atomAddF(float* p, float v) { unsafeAtomicAdd(p, v); }

// ---- fp8 e4m3 (OCP) codecs: manual + hardware-packed where available ----
__device__ __forceinline__ unsigned char enc8(float x) {
    unsigned xb = __float_as_uint(x);
    unsigned s = (xb >> 24) & 0x80u;
    float a = __uint_as_float(xb & 0x7FFFFFFFu);
    if (!(a < 448.f)) return (unsigned char)(s | 0x7E);
    if (a < 0.0009765625f) return (unsigned char)s;
    if (a < 0.015625f) {
        int m = (int)(a * 512.f + 0.5f);
        if (m > 7) return (unsigned char)(s | 0x08);
        return (unsigned char)(s | (unsigned)m);
    }
    unsigned u = __float_as_uint(a) + 0x80000u;
    int e = (int)(u >> 23) - 127;
    if (e > 8) return (unsigned char)(s | 0x7E);
    unsigned m = (u >> 20) & 7u;
    return (unsigned char)(s | ((unsigned)(e + 7) << 3) | m);
}
__device__ __forceinline__ float dec8(unsigned char c) {
    unsigned s = c & 0x80u, e = (c >> 3) & 0xFu, m = c & 7u;
    float v = (e == 0) ? (float)m * 0.001953125f
                       : __uint_as_float(((e + 120u) << 23) | (m << 20));
    return s ? -v : v;
}

typedef float fx2 __attribute__((ext_vector_type(2)));

#if defined(__has_builtin)
#if __has_builtin(__builtin_amdgcn_cvt_pk_f32_fp8) && __has_builtin(__builtin_amdgcn_cvt_pk_fp8_f32)
#define HWFP8 1
#endif
#endif

__device__ __forceinline__ void dec4(unsigned w, float& v0, float& v1, float& v2, float& v3) {
#ifdef HWFP8
    fx2 lo = __builtin_amdgcn_cvt_pk_f32_fp8((int)w, false);
    fx2 hi = __builtin_amdgcn_cvt_pk_f32_fp8((int)w, true);
    v0 = lo.x; v1 = lo.y; v2 = hi.x; v3 = hi.y;
#else
    v0 = dec8(w & 0xff); v1 = dec8((w >> 8) & 0xff);
    v2 = dec8((w >> 16) & 0xff); v3 = dec8((w >> 24) & 0xff);
#endif
}
__device__ __forceinline__ unsigned enc4(float v0, float v1, float v2, float v3) {
#ifdef HWFP8
    int w = __builtin_amdgcn_cvt_pk_fp8_f32(v0, v1, 0, false);
    w = __builtin_amdgcn_cvt_pk_fp8_f32(v2, v3, w, true);
    return (unsigned)w;
#else
    return (unsigned)enc8(v0) | ((unsigned)enc8(v1) << 8)
         | ((unsigned)enc8(v2) << 16) | ((unsigned)enc8(v3) << 24);
#endif
}
__device__ __forceinline__ unsigned char enc1(float v) {
#ifdef HWFP8
    return (unsigned char)(__builtin_amdgcn_cvt_pk_fp8_f32(v, 0.f, 0, false) & 0xff);
#else
    return enc8(v);
#endif
}
__device__ __forceinline__ float dec1(unsigned char c) {
#ifdef HWFP8
    fx2 lo = __builtin_amdgcn_cvt_pk_f32_fp8((int)(unsigned)c, false);
    return lo.x;
#else
    return dec8(c);
#endif
}

typedef _Float16 f16t;
typedef _Float16 f16x8 __attribute__((ext_vector_type(8)));
typedef float f32x4 __attribute__((ext_vector_type(4)));

__device__ __forceinline__ void stF(float* p, float v) { *p = v; }
__device__ __forceinline__ void stF(__half* p, float v) { *p = __float2half(v); }

// ---------------- tiny utility kernels ----------------

__global__ void zero_f32_v6(float* __restrict__ p, long n) {
    long s = (long)gridDim.x * blockDim.x;
    for (long i = blockIdx.x * (long)blockDim.x + threadIdx.x; i < n; i += s) p[i] = 0.f;
}
__global__ void zero_i32_v8(int* __restrict__ p, int n) {
    int s = gridDim.x * blockDim.x;
    for (int i = blockIdx.x * blockDim.x + threadIdx.x; i < n; i += s) p[i] = 0;
}
__global__ void copy_i32_v8(const int* __restrict__ a, int* __restrict__ b, int n) {
    int s = gridDim.x * blockDim.x;
    for (int i = blockIdx.x * blockDim.x + threadIdx.x; i < n; i += s) b[i] = a[i];
}
__global__ void labels_v6(float* __restrict__ out, int n) {
    int i = blockIdx.x * blockDim.x + threadIdx.x;
    if (i < n) out[i] = (float)i;
}

// ---------------- CSR build ----------------

__global__ void hist_dst_v8(const int* __restrict__ ei, int* __restrict__ deg, int E) {
    int s = gridDim.x * blockDim.x;
    for (int e = blockIdx.x * blockDim.x + threadIdx.x; e < E; e += s)
        atomicAdd(&deg[ei[E + e]], 1);
}
__global__ void hist_b_v8(const int* __restrict__ b, int* __restrict__ deg, int n) {
    int s = gridDim.x * blockDim.x;
    for (int i = blockIdx.x * blockDim.x + threadIdx.x; i < n; i += s)
        atomicAdd(&deg[b[i]], 1);
}

__global__ __launch_bounds__(256) void scan_excl_v8(const int* __restrict__ in,
                                                    int* __restrict__ out, int n) {
    __shared__ int part[256];
    int span = (n + 255) / 256;
    int t = threadIdx.x;
    int s0 = t * span, s1 = min(s0 + span, n);
    int sum = 0;
    for (int i = s0; i < s1; ++i) sum += in[i];
    part[t] = sum;
    __syncthreads();
    int v = sum;
    for (int off = 1; off < 256; off <<= 1) {
        int u = (t >= off) ? part[t - off] : 0;
        __syncthreads();
        part[t] += u;
        __syncthreads();
    }
    int run = part[t] - v;
    for (int i = s0; i < s1; ++i) { out[i] = run; run += in[i]; }
    if (t == 255) out[n] = run;
}

__global__ __launch_bounds__(256) void scan_bsum_v10(const int* __restrict__ in,
                                                     int* __restrict__ bsum, int n) {
    __shared__ int red[256];
    int b = blockIdx.x, t = threadIdx.x;
    int base = b * SCB + t * 8;
    int s = 0;
#pragma unroll
    for (int i = 0; i < 8; ++i) { int idx = base + i; if (idx < n) s += in[idx]; }
    red[t] = s; __syncthreads();
#pragma unroll
    for (int o = 128; o > 0; o >>= 1) {
        if (t < o) red[t] += red[t + o];
        __syncthreads();
    }
    if (t == 0) bsum[b] = red[0];
}

__global__ __launch_bounds__(256) void scan_top_v10(int* __restrict__ bsum, int nb,
                                                    int* __restrict__ total_out) {
    __shared__ int part[256];
    int t = threadIdx.x;
    int v = (t < nb) ? bsum[t] : 0;
    part[t] = v;
    __syncthreads();
    for (int o = 1; o < 256; o <<= 1) {
        int u = (t >= o) ? part[t - o] : 0;
        __syncthreads();
        part[t] += u;
        __syncthreads();
    }
    if (t < nb) bsum[t] = part[t] - v;
    if (t == 255) *total_out = part[255];
}

__global__ __launch_bounds__(256) void scan_fill_v10(const int* __restrict__ in,
                                                     const int* __restrict__ bsum,
                                                     int* __restrict__ out, int n) {
    __shared__ int red[256];
    int b = blockIdx.x, t = threadIdx.x;
    int base = b * SCB + t * 8;
    int v[8]; int s = 0;
#pragma unroll
    for (int i = 0; i < 8; ++i) { int idx = base + i; v[i] = (idx < n) ? in[idx] : 0; s += v[i]; }
    red[t] = s;
    __syncthreads();
    int self = s;
    for (int o = 1; o < 256; o <<= 1) {
        int u = (t >= o) ? red[t - o] : 0;
        __syncthreads();
        red[t] += u;
        __syncthreads();
    }
    int run = bsum[b] + red[t] - self;
#pragma unroll
    for (int i = 0; i < 8; ++i) { int idx = base + i; if (idx < n) out[idx] = run; run += v[i]; }
}

__global__ void fill_csr_v8(const int* __restrict__ ei, const int* __restrict__ ea,
                            int* __restrict__ cursor, int* __restrict__ csrc,
                            int* __restrict__ ccombo, int E) {
    int s = gridDim.x * blockDim.x;
    for (int e = blockIdx.x * blockDim.x + threadIdx.x; e < E; e += s) {
        int dst = ei[E + e];
        int pos = atomicAdd(&cursor[dst], 1);
        csrc[pos] = ei[e];
        ccombo[pos] = ea[2 * e] * 3 + ea[2 * e + 1];
    }
}

__global__ void tbl_v8(const float* __restrict__ ee1, const float* __restrict__ ee2,
                       float* __restrict__ tbl) {
    int idx = blockIdx.x * blockDim.x + threadIdx.x;
    if (idx >= NLAYERS * NCOMBO * EMB) return;
    int j = idx % EMB;
    int cb = (idx / EMB) % NCOMBO;
    int l = idx / (EMB * NCOMBO);
    tbl[idx] = ee1[(l * 6 + cb / 3) * EMB + j] + ee2[(l * 3 + cb % 3) * EMB + j];
}

// f16 weight transpose+pad (projection head)
__global__ void wtrans_v9(const float* __restrict__ W, f16t* __restrict__ Wt,
                          int K, int N, int Kpad) {
    int idx = blockIdx.x * blockDim.x + threadIdx.x;
    if (idx >= N * Kpad) return;
    int n = idx / Kpad, k = idx - n * Kpad;
    Wt[idx] = (k < K) ? (f16t)W[(size_t)k * N + n] : (f16t)0.f;
}

// fp8 weight transpose+pad (MLP) — HW cvt
__global__ void wtrans8_v22(const float* __restrict__ W, unsigned char* __restrict__ Wt,
                            int K, int N, int Kpad) {
    int idx = blockIdx.x * blockDim.x + threadIdx.x;
    if (idx >= N * Kpad) return;
    int n = idx / Kpad, k = idx - n * Kpad;
    Wt[idx] = (k < K) ? enc1(W[(size_t)k * N + n]) : 0;
}

// ---------------- node init (HW packed cvt, dword stores, zeroes pads) ----------------

__global__ void init_h_v22(const int* __restrict__ x, const float* __restrict__ ae1,
                           const float* __restrict__ ae2, unsigned char* __restrict__ h,
                           int N) {
    int s = gridDim.x * blockDim.x;
    int total = N * (HS / 4);
    for (int idx = blockIdx.x * blockDim.x + threadIdx.x; idx < total; idx += s) {
        int i = idx / (HS / 4), d = idx - i * (HS / 4);
        int j = d * 4;
        int x0 = x[2 * i] * EMB, x1 = x[2 * i + 1] * EMB;
        unsigned out = 0;
        if (j + 3 < EMB) {
            float v0 = ae1[x0 + j]     + ae2[x1 + j];
            float v1 = ae1[x0 + j + 1] + ae2[x1 + j + 1];
            float v2 = ae1[x0 + j + 2] + ae2[x1 + j + 2];
            float v3 = ae1[x0 + j + 3] + ae2[x1 + j + 3];
            out = enc4(v0, v1, v2, v3);
        } else {
#pragma unroll
            for (int t = 0; t < 4; ++t) {
                int jj = j + t;
                unsigned char b = 0;
                if (jj < EMB) b = enc1(ae1[x0 + jj] + ae2[x1 + jj]);
                out |= (unsigned)b << (8 * t);
            }
        }
        *(unsigned*)(h + (size_t)i * HS + j) = out;
    }
}

// ---------------- CSR gather + fused BN/ReLU; 2 edges in flight (verified v18) ----------------
template<bool BN>
__global__ __launch_bounds__(256)
void gather_v18(const unsigned char* __restrict__ h, const int* __restrict__ rp,
                const int* __restrict__ csrc, const int* __restrict__ ccombo,
                const float* __restrict__ tbl, const float* __restrict__ scl,
                const float* __restrict__ sft, unsigned char* __restrict__ aggc,
                int c0, int c1) {
    __shared__ float T[NCOMBO * EMB];
    __shared__ float SC[EMB + 4];
    __shared__ float SF[EMB + 4];
    for (int t = threadIdx.x; t < NCOMBO * EMB; t += 256) T[t] = tbl[t];
    if (BN) {
        for (int t = threadIdx.x; t < EMB; t += 256) { SC[t] = scl[t]; SF[t] = sft[t]; }
    }
    __syncthreads();
    int wid = (blockIdx.x * blockDim.x + threadIdx.x) >> 6;
    int lane = threadIdx.x & 63;
    int nw = (gridDim.x * blockDim.x) >> 6;
    const int jt = 256 + lane;
    float4 sc4, sf4; float sct = 1.f, sff = 0.f;
    if (BN) {
        sc4 = *(const float4*)&SC[lane << 2];
        sf4 = *(const float4*)&SF[lane << 2];
        if (lane < 44) { sct = SC[jt]; sff = SF[jt]; }
    }
#define BNAPP(val, sc, sf) { if (BN) (val) = fmaxf(fmaf((val), (sc), (sf)), 0.f); }
    for (int i = c0 + wid; i < c1; i += nw) {
        int p0 = rp[i], p1 = rp[i + 1];
        float a0, a1, a2, a3, at = 0.f;
        {
            const unsigned char* hr = h + (size_t)i * HS;
            unsigned w = *(const unsigned*)(hr + (lane << 2));
            float4 t4 = *(const float4*)&T[SELFCB * EMB + (lane << 2)];
            float v0, v1, v2, v3;
            dec4(w, v0, v1, v2, v3);
            BNAPP(v0, sc4.x, sf4.x); BNAPP(v1, sc4.y, sf4.y);
            BNAPP(v2, sc4.z, sf4.z); BNAPP(v3, sc4.w, sf4.w);
            a0 = v0 + t4.x; a1 = v1 + t4.y; a2 = v2 + t4.z; a3 = v3 + t4.w;
            if (lane < 44) {
                float vt = dec1(hr[jt]);
                BNAPP(vt, sct, sff);
                at = vt + T[SELFCB * EMB + jt];
            }
        }
        int p = p0;
        for (; p + 1 < p1; p += 2) {
            int sA = csrc[p],     cbA = ccombo[p];
            int sB = csrc[p + 1], cbB = ccombo[p + 1];
            const unsigned char* hA = h + (size_t)sA * HS;
            const unsigned char* hB = h + (size_t)sB * HS;
            unsigned wA = *(const unsigned*)(hA + (lane << 2));
            unsigned wB = *(const unsigned*)(hB + (lane << 2));
            float tA = 0.f, tB = 0.f;
            if (lane < 44) { tA = dec1(hA[jt]); tB = dec1(hB[jt]); }
            {
                float4 t4 = *(const float4*)&T[cbA * EMB + (lane << 2)];
                float v0, v1, v2, v3;
                dec4(wA, v0, v1, v2, v3);
                BNAPP(v0, sc4.x, sf4.x); BNAPP(v1, sc4.y, sf4.y);
                BNAPP(v2, sc4.z, sf4.z); BNAPP(v3, sc4.w, sf4.w);
                a0 += v0 + t4.x; a1 += v1 + t4.y; a2 += v2 + t4.z; a3 += v3 + t4.w;
                if (lane < 44) {
                    BNAPP(tA, sct, sff);
                    at += tA + T[cbA * EMB + jt];
                }
            }
            {
                float4 t4 = *(const float4*)&T[cbB * EMB + (lane << 2)];
                float v0, v1, v2, v3;
                dec4(wB, v0, v1, v2, v3);
                BNAPP(v0, sc4.x, sf4.x); BNAPP(v1, sc4.y, sf4.y);
                BNAPP(v2, sc4.z, sf4.z); BNAPP(v3, sc4.w, sf4.w);
                a0 += v0 + t4.x; a1 += v1 + t4.y; a2 += v2 + t4.z; a3 += v3 + t4.w;
                if (lane < 44) {
                    BNAPP(tB, sct, sff);
                    at += tB + T[cbB * EMB + jt];
                }
            }
        }
        if (p < p1) {
            int sA = csrc[p], cbA = ccombo[p];
            const unsigned char* hA = h + (size_t)sA * HS;
            unsigned wA = *(const unsigned*)(hA + (lane << 2));
            float4 t4 = *(const float4*)&T[cbA * EMB + (lane << 2)];
            float v0, v1, v2, v3;
            dec4(wA, v0, v1, v2, v3);
            BNAPP(v0, sc4.x, sf4.x); BNAPP(v1, sc4.y, sf4.y);
            BNAPP(v2, sc4.z, sf4.z); BNAPP(v3, sc4.w, sf4.w);
            a0 += v0 + t4.x; a1 += v1 + t4.y; a2 += v2 + t4.z; a3 += v3 + t4.w;
            if (lane < 44) {
                float vt = dec1(hA[jt]);
                BNAPP(vt, sct, sff);
                at += vt + T[cbA * EMB + jt];
            }
        }
        unsigned char* out = aggc + (size_t)(i - c0) * KP1;
        *(unsigned*)(out + (lane << 2)) = enc4(a0, a1, a2, a3);
        if (lane < 44) out[jt] = enc1(at);
    }
#undef BNAPP
}

// ---------------- FP8 MFMA GEMM v20 (verified): two k-tiles per barrier pair ----------------
template<int MODE, bool STATS>   // MODE: 1=+bias, 2=+bias+relu
__global__ __launch_bounds__(256)
void fast_gemm8_v20(const unsigned char* __restrict__ A, int lda,
                    const unsigned char* __restrict__ Bt, int ldb,
                    const float* __restrict__ bias, unsigned char* __restrict__ C,
                    int ldc, int M, int N, int Kpad, int gx,
                    float* __restrict__ sums)
{
    __shared__ char smem[36864];
    const int tid = threadIdx.x;
    const int lane = tid & 63;
    const int wid = tid >> 6;
    const int wr = (wid >> 1) << 6;
    const int wc = (wid & 1) << 6;

    const int nwg = gridDim.x;
    const int q = nwg >> 3, r = nwg & 7;
    const int xcd = blockIdx.x & 7, idx = blockIdx.x >> 3;
    const int swz = (xcd < r ? xcd * (q + 1) : r * (q + 1) + (xcd - r) * q) + idx;
    const int row0 = (swz / gx) * 128;
    const int col0 = (swz % gx) * 128;

    f32x4 acc[4][4] = {};
    const int nkt = Kpad >> 6;
    const int sr = tid >> 1;
    const int skb = (tid & 1) << 5;
    const int gr = row0 + sr;
    const int gc = col0 + sr;
    const int fr = lane & 15;
    const int kbase = (lane >> 4) << 3;

#define STAGE_TILE(buf, kt_) {                                                   \
        const int k0_ = (kt_) << 6;                                              \
        {                                                                        \
            const unsigned char* src = A + (size_t)gr * lda + k0_ + skb;         \
            int4 v0 = {0,0,0,0}, v1 = {0,0,0,0};                                 \
            if (gr < M) { v0 = *(const int4*)src; v1 = *(const int4*)(src + 16);}\
            char* dst = smem + (buf) * 18432 + sr * 72 + skb;                    \
            *(long*)(dst)      = ((const long*)&v0)[0];                          \
            *(long*)(dst + 8)  = ((const long*)&v0)[1];                          \
            *(long*)(dst + 16) = ((const long*)&v1)[0];                          \
            *(long*)(dst + 24) = ((const long*)&v1)[1];                          \
        }                                                                        \
        {                                                                        \
            const unsigned char* src = Bt + (size_t)gc * ldb + k0_ + skb;        \
            int4 v0 = {0,0,0,0}, v1 = {0,0,0,0};                                 \
            if (gc < N) { v0 = *(const int4*)src; v1 = *(const int4*)(src + 16);}\
            char* dst = smem + (buf) * 18432 + 9216 + sr * 72 + skb;             \
            *(long*)(dst)      = ((const long*)&v0)[0];                          \
            *(long*)(dst + 8)  = ((const long*)&v0)[1];                          \
            *(long*)(dst + 16) = ((const long*)&v1)[0];                          \
            *(long*)(dst + 24) = ((const long*)&v1)[1];                          \
        }                                                                        \
    }

#define MFMA_TILE(buf) {                                                         \
        const char* AlB = smem + (buf) * 18432;                                  \
        const char* BlB = AlB + 9216;                                            \
        _Pragma("unroll")                                                        \
        for (int ks = 0; ks < 2; ++ks) {                                         \
            const int kg = kbase + ks * 32;                                      \
            long af[4], bf[4];                                                   \
            _Pragma("unroll")                                                    \
            for (int mi = 0; mi < 4; ++mi)                                       \
                af[mi] = *(const long*)(AlB + (wr + mi * 16 + fr) * 72 + kg);    \
            _Pragma("unroll")                                                    \
            for (int ni = 0; ni < 4; ++ni)                                       \
                bf[ni] = *(const long*)(BlB + (wc + ni * 16 + fr) * 72 + kg);    \
            _Pragma("unroll")                                                    \
            for (int mi = 0; mi < 4; ++mi)                                       \
                _Pragma("unroll")                                                \
                for (int ni = 0; ni < 4; ++ni)                                   \
                    acc[mi][ni] = __builtin_amdgcn_mfma_f32_16x16x32_fp8_fp8(    \
                        af[mi], bf[ni], acc[mi][ni], 0, 0, 0);                   \
        }                                                                        \
    }

    int kt = 0;
    for (; kt + 1 < nkt; kt += 2) {
        STAGE_TILE(0, kt)
        STAGE_TILE(1, kt + 1)
        __syncthreads();
        MFMA_TILE(0)
        MFMA_TILE(1)
        __syncthreads();
    }
    if (kt < nkt) {
        STAGE_TILE(0, kt)
        __syncthreads();
        MFMA_TILE(0)
        __syncthreads();
    }
#undef STAGE_TILE
#undef MFMA_TILE

    char* Cl = smem;
    float* Sred = (float*)(smem + 18432);
    float* Qred = (float*)(smem + 22528);
    const int rb = (lane >> 4) << 2;
    const int slot = ((wid >> 1) << 2) | (lane >> 4);
#pragma unroll
    for (int ni = 0; ni < 4; ++ni) {
        const int cb = wc + ni * 16 + fr;
        const int c = col0 + cb;
        const float bv = (c < N) ? bias[c] : 0.f;
        float lsum = 0.f, lsq = 0.f;
#pragma unroll
        for (int mi = 0; mi < 4; ++mi) {
#pragma unroll
            for (int i = 0; i < 4; ++i) {
                const int rloc = wr + mi * 16 + rb + i;
                float v = acc[mi][ni][i] + bv;
                if (MODE == 2) v = fmaxf(v, 0.f);
                Cl[rloc * 144 + cb] = (char)enc1(v);
                if (STATS && (row0 + rloc) < M && c < N) {
                    lsum += v; lsq = fmaf(v, v, lsq);
                }
            }
        }
        if (STATS) { Sred[cb * 8 + slot] = lsum; Qred[cb * 8 + slot] = lsq; }
    }
    __syncthreads();
    {
        const int rloc = tid >> 1;
        const int half = (tid & 1) << 6;
        const int grow = row0 + rloc;
        if (grow < M) {
            int cmax = ldc - col0; if (cmax > 128) cmax = 128;
            unsigned char* dst = C + (size_t)grow * ldc + col0;
            const char* srcl = Cl + rloc * 144 + half;
#pragma unroll
            for (int qi = 0; qi < 4; ++qi) {
                if (half + qi * 16 + 16 <= cmax)
                    *(int4*)(dst + half + qi * 16) = *(const int4*)(srcl + qi * 16);
            }
        }
    }
    if (STATS) {
        if (tid < 128) {
            const int c = col0 + tid;
            if (c < N) {
                float s = 0.f, qq = 0.f;
#pragma unroll
                for (int k = 0; k < 8; ++k) { s += Sred[tid * 8 + k]; qq += Qred[tid * 8 + k]; }
                atomAddF(&sums[c], s);
                atomAddF(&sums[EMB + c], qq);
            }
        }
    }
}

// ---------------- F16 MFMA GEMM (projection head + logits; verified v12) ----------------
template<typename TO, int MODE>   // 1=+bias, 2=+bias+relu, 3=*scale+clamp
__global__ __launch_bounds__(256)
void fast_gemm_v12(const f16t* __restrict__ A, int lda,
                   const f16t* __restrict__ Bt, int ldb,
                   const float* __restrict__ bias, TO* __restrict__ C, int ldc,
                   int M, int N, int Kpad, float scale)
{
    __shared__ f16t Al[128][76];
    __shared__ f16t Bl[128][76];
    const int tid = threadIdx.x;
    const int lane = tid & 63;
    const int wid = tid >> 6;
    const int wr = (wid >> 1) << 6;
    const int wc = (wid & 1) << 6;
    const int row0 = blockIdx.y * 128;
    const int col0 = blockIdx.x * 128;
    f32x4 acc[4][4] = {};
    const int nkt = Kpad >> 6;
    const int sr = tid >> 1;
    const int skb = (tid & 1) << 5;

    for (int kt = 0; kt < nkt; ++kt) {
        const int k0 = kt << 6;
        {
            const int gr = row0 + sr;
            const f16t* src = A + (size_t)gr * lda + k0 + skb;
            f16x8 v0 = {}, v1 = {}, v2 = {}, v3 = {};
            if (gr < M) {
                v0 = *(const f16x8*)(src);
                v1 = *(const f16x8*)(src + 8);
                v2 = *(const f16x8*)(src + 16);
                v3 = *(const f16x8*)(src + 24);
            }
            *(f16x8*)&Al[sr][skb]      = v0;
            *(f16x8*)&Al[sr][skb + 8]  = v1;
            *(f16x8*)&Al[sr][skb + 16] = v2;
            *(f16x8*)&Al[sr][skb + 24] = v3;
        }
        {
            const int gc = col0 + sr;
            const f16t* src = Bt + (size_t)gc * ldb + k0 + skb;
            f16x8 v0 = {}, v1 = {}, v2 = {}, v3 = {};
            if (gc < N) {
                v0 = *(const f16x8*)(src);
                v1 = *(const f16x8*)(src + 8);
                v2 = *(const f16x8*)(src + 16);
                v3 = *(const f16x8*)(src + 24);
            }
            *(f16x8*)&Bl[sr][skb]      = v0;
            *(f16x8*)&Bl[sr][skb + 8]  = v1;
            *(f16x8*)&Bl[sr][skb + 16] = v2;
            *(f16x8*)&Bl[sr][skb + 24] = v3;
        }
        __syncthreads();
        const int fr = lane & 15;
        const int kbase = (lane >> 4) << 3;
#pragma unroll
        for (int ks = 0; ks < 2; ++ks) {
            const int kg8 = kbase + ks * 32;
            f16x8 af[4], bf[4];
#pragma unroll
            for (int mi = 0; mi < 4; ++mi)
                af[mi] = *(const f16x8*)&Al[wr + mi * 16 + fr][kg8];
#pragma unroll
            for (int ni = 0; ni < 4; ++ni)
                bf[ni] = *(const f16x8*)&Bl[wc + ni * 16 + fr][kg8];
#pragma unroll
            for (int mi = 0; mi < 4; ++mi)
#pragma unroll
                for (int ni = 0; ni < 4; ++ni)
                    acc[mi][ni] = __builtin_amdgcn_mfma_f32_16x16x32_f16(
                        af[mi], bf[ni], acc[mi][ni], 0, 0, 0);
        }
        __syncthreads();
    }
    const int fr = lane & 15;
    const int rb = (lane >> 4) << 2;
#pragma unroll
    for (int ni = 0; ni < 4; ++ni) {
        const int c = col0 + wc + ni * 16 + fr;
        if (c >= N) continue;
        const float bv = (MODE == 1 || MODE == 2) ? bias[c] : 0.f;
#pragma unroll
        for (int mi = 0; mi < 4; ++mi) {
#pragma unroll
            for (int i = 0; i < 4; ++i) {
                const int r = row0 + wr + mi * 16 + rb + i;
                if (r >= M) continue;
                float v = acc[mi][ni][i];
                if (MODE == 1 || MODE == 2) v += bv;
                if (MODE == 2) v = fmaxf(v, 0.f);
                v *= scale;
                if (MODE == 3) v = fmaxf(-26.f, fminf(26.f, v));
                stF(&C[(size_t)r * ldc + c], v);
            }
        }
    }
}

// ---------------- BN finalize ----------------

__global__ void bn_finalize_v6(const float* __restrict__ sums,
                               const float* __restrict__ gamma, const float* __restrict__ beta,
                               float* __restrict__ scl, float* __restrict__ sft, float inv_n) {
    int j = threadIdx.x;
    if (j < EMB) {
        float m = sums[j] * inv_n;
        float var = sums[EMB + j] * inv_n - m * m;
        float sc = gamma[j] * rsqrtf(var + 1e-5f);
        scl[j] = sc;
        sft[j] = beta[j] - m * sc;
    }
}

// ---------------- pooling (segment mean + final-layer BN affine, exact) ----------------

__global__ __launch_bounds__(256) void pool_seg_v11(const unsigned char* __restrict__ h,
                                                    const int* __restrict__ gptr,
                                                    const float* __restrict__ scl,
                                                    const float* __restrict__ sft,
                                                    __half* __restrict__ poolh) {
    int g = blockIdx.x;
    int s0 = gptr[g], s1 = gptr[g + 1];
    float inv = (s1 > s0) ? 1.f / (float)(s1 - s0) : 0.f;
    for (int j = threadIdx.x; j < EMB; j += 256) {
        float s = 0.f;
        for (int r = s0; r < s1; ++r) s += dec1(h[(size_t)r * HS + j]);
        float mv = (s1 > s0) ? fmaf(s * inv, scl[j], sft[j]) : 0.f;
        poolh[(size_t)g * KP1 + j] = __float2half(mv);
    }
}

// ---------------- row normalize -> f16 padded row ----------------

__global__ __launch_bounds__(256) void rownorm_f16_v12(const float* __restrict__ f,
                                                       f16t* __restrict__ fh) {
    __shared__ float red[256];
    __shared__ float inv;
    int r = blockIdx.x, tid = threadIdx.x;
    const float* row = f + (size_t)r * EMB;
    float s = 0.f;
    for (int j = tid; j < EMB; j += 256) { float v = row[j]; s = fmaf(v, v, s); }
    red[tid] = s;
    __syncthreads();
#pragma unroll
    for (int o = 128; o > 0; o >>= 1) {
        if (tid < o) red[tid] += red[tid + o];
        __syncthreads();
    }
    if (tid == 0) inv = rsqrtf(fmaxf(red[0], 1e-30f));
    __syncthreads();
    float iv = inv;
    for (int j = tid; j < KP1; j += 256)
        fh[(size_t)r * KP1 + j] = (j < EMB) ? (f16t)(row[j] * iv) : (f16t)0.f;
}

// ---------------- host launcher ----------------

extern "C" void kernel_launch(void* const* d_in, const int* in_sizes, int n_in,
                              void* d_out, int out_size, void* d_ws, size_t ws_size,
                              hipStream_t stream) {
    const int N = in_sizes[0] / 2;
    const int E = in_sizes[1] / 2;

    const float* atom1 = (const float*)d_in[8];
    const float* atom2 = (const float*)d_in[9];
    const float* ee1   = (const float*)d_in[10];
    const float* ee2   = (const float*)d_in[11];
    const float* W1    = (const float*)d_in[12];
    const float* bm1   = (const float*)d_in[13];
    const float* W2    = (const float*)d_in[14];
    const float* bm2   = (const float*)d_in[15];
    const float* gamma = (const float*)d_in[16];
    const float* beta  = (const float*)d_in[17];
    const float* Wp1   = (const float*)d_in[18];
    const float* bp1   = (const float*)d_in[19];
    const float* Wp2   = (const float*)d_in[20];
    const float* bp2   = (const float*)d_in[21];

    float* ob = (float*)d_out;

    unsigned char* h0 = (unsigned char*)d_out;   // overlays logits region
    bool h0_fits = ((size_t)N * HS) <= ((size_t)NG * NG * 4 - 256);

    size_t off = 0;
    char* base = (char*)d_ws;
    auto take = [&](size_t bytes) -> char* {
        char* p = base + off;
        off += (bytes + 255) & ~(size_t)255;
        return p;
    };
    unsigned char* h1 = (unsigned char*)take((size_t)N * HS);
    float* fbuf   = (float*)take((size_t)NG * EMB * 4);
    f16t*  fh     = (f16t*)take((size_t)2 * NG * KP1 * 2);
    float* sums   = (float*)take(2 * EMB * 4);
    float* scl    = (float*)take((size_t)NLAYERS * EMB * 4);
    float* sft    = (float*)take((size_t)NLAYERS * EMB * 4);
    int*   deg    = (int*)take((size_t)N * 4);
    int*   rp     = (int*)take((size_t)(N + 1) * 4);
    int*   cursor = (int*)take((size_t)N * 4);
    int*   csrc   = (int*)take((size_t)E * 4);
    int*   ccombo = (int*)take((size_t)E * 4);
    int*   bsum   = (int*)take(256 * 4);
    int*   gdeg   = (int*)take((size_t)NG * 4);
    int*   gptr   = (int*)take((size_t)(NG + 1) * 4);
    float* tbl    = (float*)take((size_t)NLAYERS * NCOMBO * EMB * 4);
    unsigned char* W1t8 = (unsigned char*)take((size_t)NLAYERS * NHID * KP1);
    unsigned char* W2t8 = (unsigned char*)take((size_t)NLAYERS * EMB * KP2);
    f16t*  Wp1t   = (f16t*)take((size_t)EMB * KP1 * 2);
    f16t*  Wp2t   = (f16t*)take((size_t)EMB * KP1 * 2);
    __half* poolh = (__half*)take((size_t)NG * KP1 * 2);
    __half* p1h   = (__half*)take((size_t)NG * KP1 * 2);

    long CN = 0;
    if (h0_fits && ws_size > off + 1024) {
        CN = (long)((ws_size - off - 1024) / (KP1 + KP2));
        if (CN > N) CN = N;
    }
    if (CN < 1024) {
        zero_f32_v6<<<2048, 256, 0, stream>>>(ob, (long)NG * NG);
        labels_v6<<<(NG + 255) / 256, 256, 0, stream>>>(ob + (size_t)NG * NG, NG);
        return;
    }
    unsigned char* aggc = (unsigned char*)take((size_t)CN * KP1);
    unsigned char* z    = (unsigned char*)take((size_t)CN * KP2);

    tbl_v8<<<(NLAYERS * NCOMBO * EMB + 255) / 256, 256, 0, stream>>>(ee1, ee2, tbl);
    for (int l = 0; l < NLAYERS; ++l) {
        wtrans8_v22<<<(NHID * KP1 + 255) / 256, 256, 0, stream>>>(
            W1 + (size_t)l * EMB * NHID, W1t8 + (size_t)l * NHID * KP1, EMB, NHID, KP1);
        wtrans8_v22<<<(EMB * KP2 + 255) / 256, 256, 0, stream>>>(
            W2 + (size_t)l * NHID * EMB, W2t8 + (size_t)l * EMB * KP2, NHID, EMB, KP2);
    }
    wtrans_v9<<<(EMB * KP1 + 255) / 256, 256, 0, stream>>>(Wp1, Wp1t, EMB, EMB, KP1);
    wtrans_v9<<<(EMB * KP1 + 255) / 256, 256, 0, stream>>>(Wp2, Wp2t, EMB, EMB, KP1);
    zero_f32_v6<<<2048, 256, 0, stream>>>((float*)aggc, CN * (KP1 / 4));
    zero_f32_v6<<<2048, 256, 0, stream>>>((float*)z, CN * (KP2 / 4));
    zero_f32_v6<<<1024, 256, 0, stream>>>((float*)poolh, (long)NG * (KP1 / 2));
    zero_f32_v6<<<1024, 256, 0, stream>>>((float*)p1h, (long)NG * (KP1 / 2));

    const int nb = (N + SCB - 1) / SCB;

    for (int enc = 0; enc < 2; ++enc) {
        const int* x  = (const int*)d_in[enc * 4 + 0];
        const int* ei = (const int*)d_in[enc * 4 + 1];
        const int* ea = (const int*)d_in[enc * 4 + 2];
        const int* bi = (const int*)d_in[enc * 4 + 3];

        zero_i32_v8<<<256, 256, 0, stream>>>(deg, N);
        hist_dst_v8<<<1024, 256, 0, stream>>>(ei, deg, E);
        scan_bsum_v10<<<nb, 256, 0, stream>>>(deg, bsum, N);
        scan_top_v10<<<1, 256, 0, stream>>>(bsum, nb, rp + N);
        scan_fill_v10<<<nb, 256, 0, stream>>>(deg, bsum, rp, N);
        copy_i32_v8<<<256, 256, 0, stream>>>(rp, cursor, N);
        fill_csr_v8<<<1024, 256, 0, stream>>>(ei, ea, cursor, csrc, ccombo, E);
        zero_i32_v8<<<64, 256, 0, stream>>>(gdeg, NG);
        hist_b_v8<<<1024, 256, 0, stream>>>(bi, gdeg, N);
        scan_excl_v8<<<1, 256, 0, stream>>>(gdeg, gptr, NG);

        unsigned char* hc = h0;
        unsigned char* hn = h1;
        init_h_v22<<<4096, 256, 0, stream>>>(x, atom1, atom2, hc, N);

        for (int l = 0; l < NLAYERS; ++l) {
            const unsigned char* W1l = W1t8 + (size_t)l * NHID * KP1;
            const unsigned char* W2l = W2t8 + (size_t)l * EMB * KP2;
            const float* tl = tbl + (size_t)l * NCOMBO * EMB;
            const float* scp = scl + (size_t)(l - 1) * EMB;
            const float* sfp = sft + (size_t)(l - 1) * EMB;

            zero_f32_v6<<<1, 1024, 0, stream>>>(sums, 2 * EMB);

            for (long c0 = 0; c0 < N; c0 += CN) {
                int m = (int)((N - c0 < CN) ? (N - c0) : CN);
                if (l == 0)
                    gather_v18<false><<<2048, 256, 0, stream>>>(
                        hc, rp, csrc, ccombo, tl, nullptr, nullptr,
                        aggc, (int)c0, (int)(c0 + m));
                else
                    gather_v18<true><<<2048, 256, 0, stream>>>(
                        hc, rp, csrc, ccombo, tl, scp, sfp,
                        aggc, (int)c0, (int)(c0 + m));
                int gx1 = (NHID + 127) / 128, gy1 = (m + 127) / 128;
                fast_gemm8_v20<2, false><<<gx1 * gy1, 256, 0, stream>>>(
                    aggc, KP1, W1l, KP1, bm1 + l * NHID,
                    z, KP2, m, NHID, KP1, gx1, nullptr);
                int gx2 = (EMB + 127) / 128;
                fast_gemm8_v20<1, true><<<gx2 * gy1, 256, 0, stream>>>(
                    z, KP2, W2l, KP2, bm2 + l * EMB,
                    hn + (size_t)c0 * HS, HS, m, EMB, KP2, gx2, sums);
            }

            bn_finalize_v6<<<1, 320, 0, stream>>>(sums, gamma + l * EMB, beta + l * EMB,
                                                  scl + (size_t)l * EMB,
                                                  sft + (size_t)l * EMB, 1.f / (float)N);
            unsigned char* t = hc; hc = hn; hn = t;
        }
        // NLAYERS=5 (odd): final raw state in h1; h0 (d_out overlay) dead.

        pool_seg_v11<<<NG, 256, 0, stream>>>(hc, gptr,
                                             scl + (size_t)(NLAYERS - 1) * EMB,
                                             sft + (size_t)(NLAYERS - 1) * EMB, poolh);

        dim3 gp((EMB + 127) / 128, (NG + 127) / 128);
        fast_gemm_v12<__half, 2><<<gp, 256, 0, stream>>>(
            (const f16t*)poolh, KP1, Wp1t, KP1, bp1, p1h, KP1, NG, EMB, KP1, 1.f);
        fast_gemm_v12<float, 1><<<gp, 256, 0, stream>>>(
            (const f16t*)p1h, KP1, Wp2t, KP1, bp2, fbuf, EMB, NG, EMB, KP1, 1.f);
        rownorm_f16_v12<<<NG, 256, 0, stream>>>(fbuf, fh + (size_t)enc * NG * KP1);
    }

    // logits = (f0h @ f1h^T) * 25, clamped, f16 MFMA; then labels
    f16t* f0h = fh;
    f16t* f1h = fh + (size_t)NG * KP1;
    dim3 gl(NG / 128, NG / 128);
    fast_gemm_v12<float, 3><<<gl, 256, 0, stream>>>(
        f0h, KP1, f1h, KP1, nullptr, ob, NG, NG, NG, KP1, 25.f);
    labels_v6<<<(NG + 255) / 256, 256, 0, stream>>>(ob + (size_t)NG * NG, NG);
}

// Round 23
// 4081.334 us; speedup vs baseline: 1.2372x; 1.0036x over previous
//
#include <hip/hip_runtime.h>
#include <hip/hip_bf16.h>
#include <hip/hip_fp16.h>

#define EMB 300
#define NHID 600
#define NLAYERS 5
#define NG 4096
#define NCOMBO 18
#define SELFCB 12    // a0=4 (self-loop), a1=0 -> 4*3+0
#define HS 304       // padded byte stride of fp8 node-state rows
#define KP1 320      // Kpad for K=300 (EMB)
#define KP2 640      // Kpad for K=600 (NHID)
#define SCB 2048     // scan elems per block

__device__ __forceinline__ void atomAddF(float* p, float v) { unsafeAtomicAdd(p, v); }

// ---- fp8 e4m3 (OCP) codecs: manual + hardware-packed where available ----
__device__ __forceinline__ unsigned char enc8(float x) {
    unsigned xb = __float_as_uint(x);
    unsigned s = (xb >> 24) & 0x80u;
    float a = __uint_as_float(xb & 0x7FFFFFFFu);
    if (!(a < 448.f)) return (unsigned char)(s | 0x7E);
    if (a < 0.0009765625f) return (unsigned char)s;
    if (a < 0.015625f) {
        int m = (int)(a * 512.f + 0.5f);
        if (m > 7) return (unsigned char)(s | 0x08);
        return (unsigned char)(s | (unsigned)m);
    }
    unsigned u = __float_as_uint(a) + 0x80000u;
    int e = (int)(u >> 23) - 127;
    if (e > 8) return (unsigned char)(s | 0x7E);
    unsigned m = (u >> 20) & 7u;
    return (unsigned char)(s | ((unsigned)(e + 7) << 3) | m);
}
__device__ __forceinline__ float dec8(unsigned char c) {
    unsigned s = c & 0x80u, e = (c >> 3) & 0xFu, m = c & 7u;
    float v = (e == 0) ? (float)m * 0.001953125f
                       : __uint_as_float(((e + 120u) << 23) | (m << 20));
    return s ? -v : v;
}

typedef float fx2 __attribute__((ext_vector_type(2)));

#if defined(__has_builtin)
#if __has_builtin(__builtin_amdgcn_cvt_pk_f32_fp8) && __has_builtin(__builtin_amdgcn_cvt_pk_fp8_f32)
#define HWFP8 1
#endif
#endif

__device__ __forceinline__ void dec4(unsigned w, float& v0, float& v1, float& v2, float& v3) {
#ifdef HWFP8
    fx2 lo = __builtin_amdgcn_cvt_pk_f32_fp8((int)w, false);
    fx2 hi = __builtin_amdgcn_cvt_pk_f32_fp8((int)w, true);
    v0 = lo.x; v1 = lo.y; v2 = hi.x; v3 = hi.y;
#else
    v0 = dec8(w & 0xff); v1 = dec8((w >> 8) & 0xff);
    v2 = dec8((w >> 16) & 0xff); v3 = dec8((w >> 24) & 0xff);
#endif
}
__device__ __forceinline__ unsigned enc4(float v0, float v1, float v2, float v3) {
#ifdef HWFP8
    int w = __builtin_amdgcn_cvt_pk_fp8_f32(v0, v1, 0, false);
    w = __builtin_amdgcn_cvt_pk_fp8_f32(v2, v3, w, true);
    return (unsigned)w;
#else
    return (unsigned)enc8(v0) | ((unsigned)enc8(v1) << 8)
         | ((unsigned)enc8(v2) << 16) | ((unsigned)enc8(v3) << 24);
#endif
}
__device__ __forceinline__ unsigned char enc1(float v) {
#ifdef HWFP8
    return (unsigned char)(__builtin_amdgcn_cvt_pk_fp8_f32(v, 0.f, 0, false) & 0xff);
#else
    return enc8(v);
#endif
}
__device__ __forceinline__ float dec1(unsigned char c) {
#ifdef HWFP8
    fx2 lo = __builtin_amdgcn_cvt_pk_f32_fp8((int)(unsigned)c, false);
    return lo.x;
#else
    return dec8(c);
#endif
}

typedef _Float16 f16t;
typedef _Float16 f16x8 __attribute__((ext_vector_type(8)));
typedef float f32x4 __attribute__((ext_vector_type(4)));

__device__ __forceinline__ void stF(float* p, float v) { *p = v; }
__device__ __forceinline__ void stF(__half* p, float v) { *p = __float2half(v); }

// ---------------- tiny utility kernels ----------------

__global__ void zero_f32_v6(float* __restrict__ p, long n) {
    long s = (long)gridDim.x * blockDim.x;
    for (long i = blockIdx.x * (long)blockDim.x + threadIdx.x; i < n; i += s) p[i] = 0.f;
}
__global__ void zero_i32_v8(int* __restrict__ p, int n) {
    int s = gridDim.x * blockDim.x;
    for (int i = blockIdx.x * blockDim.x + threadIdx.x; i < n; i += s) p[i] = 0;
}
__global__ void copy_i32_v8(const int* __restrict__ a, int* __restrict__ b, int n) {
    int s = gridDim.x * blockDim.x;
    for (int i = blockIdx.x * blockDim.x + threadIdx.x; i < n; i += s) b[i] = a[i];
}
__global__ void labels_v6(float* __restrict__ out, int n) {
    int i = blockIdx.x * blockDim.x + threadIdx.x;
    if (i < n) out[i] = (float)i;
}

// ---------------- CSR build ----------------

__global__ void hist_dst_v8(const int* __restrict__ ei, int* __restrict__ deg, int E) {
    int s = gridDim.x * blockDim.x;
    for (int e = blockIdx.x * blockDim.x + threadIdx.x; e < E; e += s)
        atomicAdd(&deg[ei[E + e]], 1);
}
__global__ void hist_b_v8(const int* __restrict__ b, int* __restrict__ deg, int n) {
    int s = gridDim.x * blockDim.x;
    for (int i = blockIdx.x * blockDim.x + threadIdx.x; i < n; i += s)
        atomicAdd(&deg[b[i]], 1);
}

__global__ __launch_bounds__(256) void scan_excl_v8(const int* __restrict__ in,
                                                    int* __restrict__ out, int n) {
    __shared__ int part[256];
    int span = (n + 255) / 256;
    int t = threadIdx.x;
    int s0 = t * span, s1 = min(s0 + span, n);
    int sum = 0;
    for (int i = s0; i < s1; ++i) sum += in[i];
    part[t] = sum;
    __syncthreads();
    int v = sum;
    for (int off = 1; off < 256; off <<= 1) {
        int u = (t >= off) ? part[t - off] : 0;
        __syncthreads();
        part[t] += u;
        __syncthreads();
    }
    int run = part[t] - v;
    for (int i = s0; i < s1; ++i) { out[i] = run; run += in[i]; }
    if (t == 255) out[n] = run;
}

__global__ __launch_bounds__(256) void scan_bsum_v10(const int* __restrict__ in,
                                                     int* __restrict__ bsum, int n) {
    __shared__ int red[256];
    int b = blockIdx.x, t = threadIdx.x;
    int base = b * SCB + t * 8;
    int s = 0;
#pragma unroll
    for (int i = 0; i < 8; ++i) { int idx = base + i; if (idx < n) s += in[idx]; }
    red[t] = s; __syncthreads();
#pragma unroll
    for (int o = 128; o > 0; o >>= 1) {
        if (t < o) red[t] += red[t + o];
        __syncthreads();
    }
    if (t == 0) bsum[b] = red[0];
}

__global__ __launch_bounds__(256) void scan_top_v10(int* __restrict__ bsum, int nb,
                                                    int* __restrict__ total_out) {
    __shared__ int part[256];
    int t = threadIdx.x;
    int v = (t < nb) ? bsum[t] : 0;
    part[t] = v;
    __syncthreads();
    for (int o = 1; o < 256; o <<= 1) {
        int u = (t >= o) ? part[t - o] : 0;
        __syncthreads();
        part[t] += u;
        __syncthreads();
    }
    if (t < nb) bsum[t] = part[t] - v;
    if (t == 255) *total_out = part[255];
}

__global__ __launch_bounds__(256) void scan_fill_v10(const int* __restrict__ in,
                                                     const int* __restrict__ bsum,
                                                     int* __restrict__ out, int n) {
    __shared__ int red[256];
    int b = blockIdx.x, t = threadIdx.x;
    int base = b * SCB + t * 8;
    int v[8]; int s = 0;
#pragma unroll
    for (int i = 0; i < 8; ++i) { int idx = base + i; v[i] = (idx < n) ? in[idx] : 0; s += v[i]; }
    red[t] = s;
    __syncthreads();
    int self = s;
    for (int o = 1; o < 256; o <<= 1) {
        int u = (t >= o) ? red[t - o] : 0;
        __syncthreads();
        red[t] += u;
        __syncthreads();
    }
    int run = bsum[b] + red[t] - self;
#pragma unroll
    for (int i = 0; i < 8; ++i) { int idx = base + i; if (idx < n) out[idx] = run; run += v[i]; }
}

__global__ void fill_csr_v8(const int* __restrict__ ei, const int* __restrict__ ea,
                            int* __restrict__ cursor, int* __restrict__ csrc,
                            int* __restrict__ ccombo, int E) {
    int s = gridDim.x * blockDim.x;
    for (int e = blockIdx.x * blockDim.x + threadIdx.x; e < E; e += s) {
        int dst = ei[E + e];
        int pos = atomicAdd(&cursor[dst], 1);
        csrc[pos] = ei[e];
        ccombo[pos] = ea[2 * e] * 3 + ea[2 * e + 1];
    }
}

__global__ void tbl_v8(const float* __restrict__ ee1, const float* __restrict__ ee2,
                       float* __restrict__ tbl) {
    int idx = blockIdx.x * blockDim.x + threadIdx.x;
    if (idx >= NLAYERS * NCOMBO * EMB) return;
    int j = idx % EMB;
    int cb = (idx / EMB) % NCOMBO;
    int l = idx / (EMB * NCOMBO);
    tbl[idx] = ee1[(l * 6 + cb / 3) * EMB + j] + ee2[(l * 3 + cb % 3) * EMB + j];
}

// f16 weight transpose+pad (projection head)
__global__ void wtrans_v9(const float* __restrict__ W, f16t* __restrict__ Wt,
                          int K, int N, int Kpad) {
    int idx = blockIdx.x * blockDim.x + threadIdx.x;
    if (idx >= N * Kpad) return;
    int n = idx / Kpad, k = idx - n * Kpad;
    Wt[idx] = (k < K) ? (f16t)W[(size_t)k * N + n] : (f16t)0.f;
}

// fp8 weight transpose+pad (MLP) — HW cvt
__global__ void wtrans8_v22(const float* __restrict__ W, unsigned char* __restrict__ Wt,
                            int K, int N, int Kpad) {
    int idx = blockIdx.x * blockDim.x + threadIdx.x;
    if (idx >= N * Kpad) return;
    int n = idx / Kpad, k = idx - n * Kpad;
    Wt[idx] = (k < K) ? enc1(W[(size_t)k * N + n]) : 0;
}

// ---------------- node init (HW packed cvt, dword stores, zeroes pads) ----------------

__global__ void init_h_v22(const int* __restrict__ x, const float* __restrict__ ae1,
                           const float* __restrict__ ae2, unsigned char* __restrict__ h,
                           int N) {
    int s = gridDim.x * blockDim.x;
    int total = N * (HS / 4);
    for (int idx = blockIdx.x * blockDim.x + threadIdx.x; idx < total; idx += s) {
        int i = idx / (HS / 4), d = idx - i * (HS / 4);
        int j = d * 4;
        int x0 = x[2 * i] * EMB, x1 = x[2 * i + 1] * EMB;
        unsigned out = 0;
        if (j + 3 < EMB) {
            float v0 = ae1[x0 + j]     + ae2[x1 + j];
            float v1 = ae1[x0 + j + 1] + ae2[x1 + j + 1];
            float v2 = ae1[x0 + j + 2] + ae2[x1 + j + 2];
            float v3 = ae1[x0 + j + 3] + ae2[x1 + j + 3];
            out = enc4(v0, v1, v2, v3);
        } else {
#pragma unroll
            for (int t = 0; t < 4; ++t) {
                int jj = j + t;
                unsigned char b = 0;
                if (jj < EMB) b = enc1(ae1[x0 + jj] + ae2[x1 + jj]);
                out |= (unsigned)b << (8 * t);
            }
        }
        *(unsigned*)(h + (size_t)i * HS + j) = out;
    }
}

// ---------------- CSR gather + fused BN/ReLU; 2 edges in flight (verified v18) ----------------
template<bool BN>
__global__ __launch_bounds__(256)
void gather_v18(const unsigned char* __restrict__ h, const int* __restrict__ rp,
                const int* __restrict__ csrc, const int* __restrict__ ccombo,
                const float* __restrict__ tbl, const float* __restrict__ scl,
                const float* __restrict__ sft, unsigned char* __restrict__ aggc,
                int c0, int c1) {
    __shared__ float T[NCOMBO * EMB];
    __shared__ float SC[EMB + 4];
    __shared__ float SF[EMB + 4];
    for (int t = threadIdx.x; t < NCOMBO * EMB; t += 256) T[t] = tbl[t];
    if (BN) {
        for (int t = threadIdx.x; t < EMB; t += 256) { SC[t] = scl[t]; SF[t] = sft[t]; }
    }
    __syncthreads();
    int wid = (blockIdx.x * blockDim.x + threadIdx.x) >> 6;
    int lane = threadIdx.x & 63;
    int nw = (gridDim.x * blockDim.x) >> 6;
    const int jt = 256 + lane;
    float4 sc4, sf4; float sct = 1.f, sff = 0.f;
    if (BN) {
        sc4 = *(const float4*)&SC[lane << 2];
        sf4 = *(const float4*)&SF[lane << 2];
        if (lane < 44) { sct = SC[jt]; sff = SF[jt]; }
    }
#define BNAPP(val, sc, sf) { if (BN) (val) = fmaxf(fmaf((val), (sc), (sf)), 0.f); }
    for (int i = c0 + wid; i < c1; i += nw) {
        int p0 = rp[i], p1 = rp[i + 1];
        float a0, a1, a2, a3, at = 0.f;
        {
            const unsigned char* hr = h + (size_t)i * HS;
            unsigned w = *(const unsigned*)(hr + (lane << 2));
            float4 t4 = *(const float4*)&T[SELFCB * EMB + (lane << 2)];
            float v0, v1, v2, v3;
            dec4(w, v0, v1, v2, v3);
            BNAPP(v0, sc4.x, sf4.x); BNAPP(v1, sc4.y, sf4.y);
            BNAPP(v2, sc4.z, sf4.z); BNAPP(v3, sc4.w, sf4.w);
            a0 = v0 + t4.x; a1 = v1 + t4.y; a2 = v2 + t4.z; a3 = v3 + t4.w;
            if (lane < 44) {
                float vt = dec1(hr[jt]);
                BNAPP(vt, sct, sff);
                at = vt + T[SELFCB * EMB + jt];
            }
        }
        int p = p0;
        for (; p + 1 < p1; p += 2) {
            int sA = csrc[p],     cbA = ccombo[p];
            int sB = csrc[p + 1], cbB = ccombo[p + 1];
            const unsigned char* hA = h + (size_t)sA * HS;
            const unsigned char* hB = h + (size_t)sB * HS;
            unsigned wA = *(const unsigned*)(hA + (lane << 2));
            unsigned wB = *(const unsigned*)(hB + (lane << 2));
            float tA = 0.f, tB = 0.f;
            if (lane < 44) { tA = dec1(hA[jt]); tB = dec1(hB[jt]); }
            {
                float4 t4 = *(const float4*)&T[cbA * EMB + (lane << 2)];
                float v0, v1, v2, v3;
                dec4(wA, v0, v1, v2, v3);
                BNAPP(v0, sc4.x, sf4.x); BNAPP(v1, sc4.y, sf4.y);
                BNAPP(v2, sc4.z, sf4.z); BNAPP(v3, sc4.w, sf4.w);
                a0 += v0 + t4.x; a1 += v1 + t4.y; a2 += v2 + t4.z; a3 += v3 + t4.w;
                if (lane < 44) {
                    BNAPP(tA, sct, sff);
                    at += tA + T[cbA * EMB + jt];
                }
            }
            {
                float4 t4 = *(const float4*)&T[cbB * EMB + (lane << 2)];
                float v0, v1, v2, v3;
                dec4(wB, v0, v1, v2, v3);
                BNAPP(v0, sc4.x, sf4.x); BNAPP(v1, sc4.y, sf4.y);
                BNAPP(v2, sc4.z, sf4.z); BNAPP(v3, sc4.w, sf4.w);
                a0 += v0 + t4.x; a1 += v1 + t4.y; a2 += v2 + t4.z; a3 += v3 + t4.w;
                if (lane < 44) {
                    BNAPP(tB, sct, sff);
                    at += tB + T[cbB * EMB + jt];
                }
            }
        }
        if (p < p1) {
            int sA = csrc[p], cbA = ccombo[p];
            const unsigned char* hA = h + (size_t)sA * HS;
            unsigned wA = *(const unsigned*)(hA + (lane << 2));
            float4 t4 = *(const float4*)&T[cbA * EMB + (lane << 2)];
            float v0, v1, v2, v3;
            dec4(wA, v0, v1, v2, v3);
            BNAPP(v0, sc4.x, sf4.x); BNAPP(v1, sc4.y, sf4.y);
            BNAPP(v2, sc4.z, sf4.z); BNAPP(v3, sc4.w, sf4.w);
            a0 += v0 + t4.x; a1 += v1 + t4.y; a2 += v2 + t4.z; a3 += v3 + t4.w;
            if (lane < 44) {
                float vt = dec1(hA[jt]);
                BNAPP(vt, sct, sff);
                at += vt + T[cbA * EMB + jt];
            }
        }
        unsigned char* out = aggc + (size_t)(i - c0) * KP1;
        *(unsigned*)(out + (lane << 2)) = enc4(a0, a1, a2, a3);
        if (lane < 44) out[jt] = enc1(at);
    }
#undef BNAPP
}

// ---------------- FP8 MFMA GEMM v20 (verified): two k-tiles per barrier pair ----------------
template<int MODE, bool STATS>   // MODE: 1=+bias, 2=+bias+relu
__global__ __launch_bounds__(256)
void fast_gemm8_v20(const unsigned char* __restrict__ A, int lda,
                    const unsigned char* __restrict__ Bt, int ldb,
                    const float* __restrict__ bias, unsigned char* __restrict__ C,
                    int ldc, int M, int N, int Kpad, int gx,
                    float* __restrict__ sums)
{
    __shared__ char smem[36864];
    const int tid = threadIdx.x;
    const int lane = tid & 63;
    const int wid = tid >> 6;
    const int wr = (wid >> 1) << 6;
    const int wc = (wid & 1) << 6;

    const int nwg = gridDim.x;
    const int q = nwg >> 3, r = nwg & 7;
    const int xcd = blockIdx.x & 7, idx = blockIdx.x >> 3;
    const int swz = (xcd < r ? xcd * (q + 1) : r * (q + 1) + (xcd - r) * q) + idx;
    const int row0 = (swz / gx) * 128;
    const int col0 = (swz % gx) * 128;

    f32x4 acc[4][4] = {};
    const int nkt = Kpad >> 6;
    const int sr = tid >> 1;
    const int skb = (tid & 1) << 5;
    const int gr = row0 + sr;
    const int gc = col0 + sr;
    const int fr = lane & 15;
    const int kbase = (lane >> 4) << 3;

#define STAGE_TILE(buf, kt_) {                                                   \
        const int k0_ = (kt_) << 6;                                              \
        {                                                                        \
            const unsigned char* src = A + (size_t)gr * lda + k0_ + skb;         \
            int4 v0 = {0,0,0,0}, v1 = {0,0,0,0};                                 \
            if (gr < M) { v0 = *(const int4*)src; v1 = *(const int4*)(src + 16);}\
            char* dst = smem + (buf) * 18432 + sr * 72 + skb;                    \
            *(long*)(dst)      = ((const long*)&v0)[0];                          \
            *(long*)(dst + 8)  = ((const long*)&v0)[1];                          \
            *(long*)(dst + 16) = ((const long*)&v1)[0];                          \
            *(long*)(dst + 24) = ((const long*)&v1)[1];                          \
        }                                                                        \
        {                                                                        \
            const unsigned char* src = Bt + (size_t)gc * ldb + k0_ + skb;        \
            int4 v0 = {0,0,0,0}, v1 = {0,0,0,0};                                 \
            if (gc < N) { v0 = *(const int4*)src; v1 = *(const int4*)(src + 16);}\
            char* dst = smem + (buf) * 18432 + 9216 + sr * 72 + skb;             \
            *(long*)(dst)      = ((const long*)&v0)[0];                          \
            *(long*)(dst + 8)  = ((const long*)&v0)[1];                          \
            *(long*)(dst + 16) = ((const long*)&v1)[0];                          \
            *(long*)(dst + 24) = ((const long*)&v1)[1];                          \
        }                                                                        \
    }

#define MFMA_TILE(buf) {                                                         \
        const char* AlB = smem + (buf) * 18432;                                  \
        const char* BlB = AlB + 9216;                                            \
        _Pragma("unroll")                                                        \
        for (int ks = 0; ks < 2; ++ks) {                                         \
            const int kg = kbase + ks * 32;                                      \
            long af[4], bf[4];                                                   \
            _Pragma("unroll")                                                    \
            for (int mi = 0; mi < 4; ++mi)                                       \
                af[mi] = *(const long*)(AlB + (wr + mi * 16 + fr) * 72 + kg);    \
            _Pragma("unroll")                                                    \
            for (int ni = 0; ni < 4; ++ni)                                       \
                bf[ni] = *(const long*)(BlB + (wc + ni * 16 + fr) * 72 + kg);    \
            _Pragma("unroll")                                                    \
            for (int mi = 0; mi < 4; ++mi)                                       \
                _Pragma("unroll")                                                \
                for (int ni = 0; ni < 4; ++ni)                                   \
                    acc[mi][ni] = __builtin_amdgcn_mfma_f32_16x16x32_fp8_fp8(    \
                        af[mi], bf[ni], acc[mi][ni], 0, 0, 0);                   \
        }                                                                        \
    }

    int kt = 0;
    for (; kt + 1 < nkt; kt += 2) {
        STAGE_TILE(0, kt)
        STAGE_TILE(1, kt + 1)
        __syncthreads();
        MFMA_TILE(0)
        MFMA_TILE(1)
        __syncthreads();
    }
    if (kt < nkt) {
        STAGE_TILE(0, kt)
        __syncthreads();
        MFMA_TILE(0)
        __syncthreads();
    }
#undef STAGE_TILE
#undef MFMA_TILE

    char* Cl = smem;
    float* Sred = (float*)(smem + 18432);
    float* Qred = (float*)(smem + 22528);
    const int rb = (lane >> 4) << 2;
    const int slot = ((wid >> 1) << 2) | (lane >> 4);
#pragma unroll
    for (int ni = 0; ni < 4; ++ni) {
        const int cb = wc + ni * 16 + fr;
        const int c = col0 + cb;
        const float bv = (c < N) ? bias[c] : 0.f;
        float lsum = 0.f, lsq = 0.f;
#pragma unroll
        for (int mi = 0; mi < 4; ++mi) {
#pragma unroll
            for (int i = 0; i < 4; ++i) {
                const int rloc = wr + mi * 16 + rb + i;
                float v = acc[mi][ni][i] + bv;
                if (MODE == 2) v = fmaxf(v, 0.f);
                Cl[rloc * 144 + cb] = (char)enc1(v);
                if (STATS && (row0 + rloc) < M && c < N) {
                    lsum += v; lsq = fmaf(v, v, lsq);
                }
            }
        }
        if (STATS) { Sred[cb * 8 + slot] = lsum; Qred[cb * 8 + slot] = lsq; }
    }
    __syncthreads();
    {
        const int rloc = tid >> 1;
        const int half = (tid & 1) << 6;
        const int grow = row0 + rloc;
        if (grow < M) {
            int cmax = ldc - col0; if (cmax > 128) cmax = 128;
            unsigned char* dst = C + (size_t)grow * ldc + col0;
            const char* srcl = Cl + rloc * 144 + half;
#pragma unroll
            for (int qi = 0; qi < 4; ++qi) {
                if (half + qi * 16 + 16 <= cmax)
                    *(int4*)(dst + half + qi * 16) = *(const int4*)(srcl + qi * 16);
            }
        }
    }
    if (STATS) {
        if (tid < 128) {
            const int c = col0 + tid;
            if (c < N) {
                float s = 0.f, qq = 0.f;
#pragma unroll
                for (int k = 0; k < 8; ++k) { s += Sred[tid * 8 + k]; qq += Qred[tid * 8 + k]; }
                atomAddF(&sums[c], s);
                atomAddF(&sums[EMB + c], qq);
            }
        }
    }
}

// ---------------- F16 MFMA GEMM (projection head + logits; verified v12) ----------------
template<typename TO, int MODE>   // 1=+bias, 2=+bias+relu, 3=*scale+clamp
__global__ __launch_bounds__(256)
void fast_gemm_v12(const f16t* __restrict__ A, int lda,
                   const f16t* __restrict__ Bt, int ldb,
                   const float* __restrict__ bias, TO* __restrict__ C, int ldc,
                   int M, int N, int Kpad, float scale)
{
    __shared__ f16t Al[128][76];
    __shared__ f16t Bl[128][76];
    const int tid = threadIdx.x;
    const int lane = tid & 63;
    const int wid = tid >> 6;
    const int wr = (wid >> 1) << 6;
    const int wc = (wid & 1) << 6;
    const int row0 = blockIdx.y * 128;
    const int col0 = blockIdx.x * 128;
    f32x4 acc[4][4] = {};
    const int nkt = Kpad >> 6;
    const int sr = tid >> 1;
    const int skb = (tid & 1) << 5;

    for (int kt = 0; kt < nkt; ++kt) {
        const int k0 = kt << 6;
        {
            const int gr = row0 + sr;
            const f16t* src = A + (size_t)gr * lda + k0 + skb;
            f16x8 v0 = {}, v1 = {}, v2 = {}, v3 = {};
            if (gr < M) {
                v0 = *(const f16x8*)(src);
                v1 = *(const f16x8*)(src + 8);
                v2 = *(const f16x8*)(src + 16);
                v3 = *(const f16x8*)(src + 24);
            }
            *(f16x8*)&Al[sr][skb]      = v0;
            *(f16x8*)&Al[sr][skb + 8]  = v1;
            *(f16x8*)&Al[sr][skb + 16] = v2;
            *(f16x8*)&Al[sr][skb + 24] = v3;
        }
        {
            const int gc = col0 + sr;
            const f16t* src = Bt + (size_t)gc * ldb + k0 + skb;
            f16x8 v0 = {}, v1 = {}, v2 = {}, v3 = {};
            if (gc < N) {
                v0 = *(const f16x8*)(src);
                v1 = *(const f16x8*)(src + 8);
                v2 = *(const f16x8*)(src + 16);
                v3 = *(const f16x8*)(src + 24);
            }
            *(f16x8*)&Bl[sr][skb]      = v0;
            *(f16x8*)&Bl[sr][skb + 8]  = v1;
            *(f16x8*)&Bl[sr][skb + 16] = v2;
            *(f16x8*)&Bl[sr][skb + 24] = v3;
        }
        __syncthreads();
        const int fr = lane & 15;
        const int kbase = (lane >> 4) << 3;
#pragma unroll
        for (int ks = 0; ks < 2; ++ks) {
            const int kg8 = kbase + ks * 32;
            f16x8 af[4], bf[4];
#pragma unroll
            for (int mi = 0; mi < 4; ++mi)
                af[mi] = *(const f16x8*)&Al[wr + mi * 16 + fr][kg8];
#pragma unroll
            for (int ni = 0; ni < 4; ++ni)
                bf[ni] = *(const f16x8*)&Bl[wc + ni * 16 + fr][kg8];
#pragma unroll
            for (int mi = 0; mi < 4; ++mi)
#pragma unroll
                for (int ni = 0; ni < 4; ++ni)
                    acc[mi][ni] = __builtin_amdgcn_mfma_f32_16x16x32_f16(
                        af[mi], bf[ni], acc[mi][ni], 0, 0, 0);
        }
        __syncthreads();
    }
    const int fr = lane & 15;
    const int rb = (lane >> 4) << 2;
#pragma unroll
    for (int ni = 0; ni < 4; ++ni) {
        const int c = col0 + wc + ni * 16 + fr;
        if (c >= N) continue;
        const float bv = (MODE == 1 || MODE == 2) ? bias[c] : 0.f;
#pragma unroll
        for (int mi = 0; mi < 4; ++mi) {
#pragma unroll
            for (int i = 0; i < 4; ++i) {
                const int r = row0 + wr + mi * 16 + rb + i;
                if (r >= M) continue;
                float v = acc[mi][ni][i];
                if (MODE == 1 || MODE == 2) v += bv;
                if (MODE == 2) v = fmaxf(v, 0.f);
                v *= scale;
                if (MODE == 3) v = fmaxf(-26.f, fminf(26.f, v));
                stF(&C[(size_t)r * ldc + c], v);
            }
        }
    }
}

// ---------------- BN finalize ----------------

__global__ void bn_finalize_v6(const float* __restrict__ sums,
                               const float* __restrict__ gamma, const float* __restrict__ beta,
                               float* __restrict__ scl, float* __restrict__ sft, float inv_n) {
    int j = threadIdx.x;
    if (j < EMB) {
        float m = sums[j] * inv_n;
        float var = sums[EMB + j] * inv_n - m * m;
        float sc = gamma[j] * rsqrtf(var + 1e-5f);
        scl[j] = sc;
        sft[j] = beta[j] - m * sc;
    }
}

// ---------------- pooling (segment mean + final-layer BN affine, exact) ----------------

__global__ __launch_bounds__(256) void pool_seg_v11(const unsigned char* __restrict__ h,
                                                    const int* __restrict__ gptr,
                                                    const float* __restrict__ scl,
                                                    const float* __restrict__ sft,
                                                    __half* __restrict__ poolh) {
    int g = blockIdx.x;
    int s0 = gptr[g], s1 = gptr[g + 1];
    float inv = (s1 > s0) ? 1.f / (float)(s1 - s0) : 0.f;
    for (int j = threadIdx.x; j < EMB; j += 256) {
        float s = 0.f;
        for (int r = s0; r < s1; ++r) s += dec1(h[(size_t)r * HS + j]);
        float mv = (s1 > s0) ? fmaf(s * inv, scl[j], sft[j]) : 0.f;
        poolh[(size_t)g * KP1 + j] = __float2half(mv);
    }
}

// ---------------- row normalize -> f16 padded row ----------------

__global__ __launch_bounds__(256) void rownorm_f16_v12(const float* __restrict__ f,
                                                       f16t* __restrict__ fh) {
    __shared__ float red[256];
    __shared__ float inv;
    int r = blockIdx.x, tid = threadIdx.x;
    const float* row = f + (size_t)r * EMB;
    float s = 0.f;
    for (int j = tid; j < EMB; j += 256) { float v = row[j]; s = fmaf(v, v, s); }
    red[tid] = s;
    __syncthreads();
#pragma unroll
    for (int o = 128; o > 0; o >>= 1) {
        if (tid < o) red[tid] += red[tid + o];
        __syncthreads();
    }
    if (tid == 0) inv = rsqrtf(fmaxf(red[0], 1e-30f));
    __syncthreads();
    float iv = inv;
    for (int j = tid; j < KP1; j += 256)
        fh[(size_t)r * KP1 + j] = (j < EMB) ? (f16t)(row[j] * iv) : (f16t)0.f;
}

// ---------------- host launcher ----------------

extern "C" void kernel_launch(void* const* d_in, const int* in_sizes, int n_in,
                              void* d_out, int out_size, void* d_ws, size_t ws_size,
                              hipStream_t stream) {
    const int N = in_sizes[0] / 2;
    const int E = in_sizes[1] / 2;

    const float* atom1 = (const float*)d_in[8];
    const float* atom2 = (const float*)d_in[9];
    const float* ee1   = (const float*)d_in[10];
    const float* ee2   = (const float*)d_in[11];
    const float* W1    = (const float*)d_in[12];
    const float* bm1   = (const float*)d_in[13];
    const float* W2    = (const float*)d_in[14];
    const float* bm2   = (const float*)d_in[15];
    const float* gamma = (const float*)d_in[16];
    const float* beta  = (const float*)d_in[17];
    const float* Wp1   = (const float*)d_in[18];
    const float* bp1   = (const float*)d_in[19];
    const float* Wp2   = (const float*)d_in[20];
    const float* bp2   = (const float*)d_in[21];

    float* ob = (float*)d_out;

    unsigned char* h0 = (unsigned char*)d_out;   // overlays logits region
    bool h0_fits = ((size_t)N * HS) <= ((size_t)NG * NG * 4 - 256);

    size_t off = 0;
    char* base = (char*)d_ws;
    auto take = [&](size_t bytes) -> char* {
        char* p = base + off;
        off += (bytes + 255) & ~(size_t)255;
        return p;
    };
    unsigned char* h1 = (unsigned char*)take((size_t)N * HS);
    float* fbuf   = (float*)take((size_t)NG * EMB * 4);
    f16t*  fh     = (f16t*)take((size_t)2 * NG * KP1 * 2);
    float* sums   = (float*)take(2 * EMB * 4);
    float* scl    = (float*)take((size_t)NLAYERS * EMB * 4);
    float* sft    = (float*)take((size_t)NLAYERS * EMB * 4);
    int*   deg    = (int*)take((size_t)N * 4);
    int*   rp     = (int*)take((size_t)(N + 1) * 4);
    int*   cursor = (int*)take((size_t)N * 4);
    int*   csrc   = (int*)take((size_t)E * 4);
    int*   ccombo = (int*)take((size_t)E * 4);
    int*   bsum   = (int*)take(256 * 4);
    int*   gdeg   = (int*)take((size_t)NG * 4);
    int*   gptr   = (int*)take((size_t)(NG + 1) * 4);
    float* tbl    = (float*)take((size_t)NLAYERS * NCOMBO * EMB * 4);
    unsigned char* W1t8 = (unsigned char*)take((size_t)NLAYERS * NHID * KP1);
    unsigned char* W2t8 = (unsigned char*)take((size_t)NLAYERS * EMB * KP2);
    f16t*  Wp1t   = (f16t*)take((size_t)EMB * KP1 * 2);
    f16t*  Wp2t   = (f16t*)take((size_t)EMB * KP1 * 2);
    __half* poolh = (__half*)take((size_t)NG * KP1 * 2);
    __half* p1h   = (__half*)take((size_t)NG * KP1 * 2);

    long CN = 0;
    if (h0_fits && ws_size > off + 1024) {
        CN = (long)((ws_size - off - 1024) / (KP1 + KP2));
        if (CN > N) CN = N;
    }
    if (CN < 1024) {
        zero_f32_v6<<<2048, 256, 0, stream>>>(ob, (long)NG * NG);
        labels_v6<<<(NG + 255) / 256, 256, 0, stream>>>(ob + (size_t)NG * NG, NG);
        return;
    }
    unsigned char* aggc = (unsigned char*)take((size_t)CN * KP1);
    unsigned char* z    = (unsigned char*)take((size_t)CN * KP2);

    tbl_v8<<<(NLAYERS * NCOMBO * EMB + 255) / 256, 256, 0, stream>>>(ee1, ee2, tbl);
    for (int l = 0; l < NLAYERS; ++l) {
        wtrans8_v22<<<(NHID * KP1 + 255) / 256, 256, 0, stream>>>(
            W1 + (size_t)l * EMB * NHID, W1t8 + (size_t)l * NHID * KP1, EMB, NHID, KP1);
        wtrans8_v22<<<(EMB * KP2 + 255) / 256, 256, 0, stream>>>(
            W2 + (size_t)l * NHID * EMB, W2t8 + (size_t)l * EMB * KP2, NHID, EMB, KP2);
    }
    wtrans_v9<<<(EMB * KP1 + 255) / 256, 256, 0, stream>>>(Wp1, Wp1t, EMB, EMB, KP1);
    wtrans_v9<<<(EMB * KP1 + 255) / 256, 256, 0, stream>>>(Wp2, Wp2t, EMB, EMB, KP1);
    zero_f32_v6<<<2048, 256, 0, stream>>>((float*)aggc, CN * (KP1 / 4));
    zero_f32_v6<<<2048, 256, 0, stream>>>((float*)z, CN * (KP2 / 4));
    zero_f32_v6<<<1024, 256, 0, stream>>>((float*)poolh, (long)NG * (KP1 / 2));
    zero_f32_v6<<<1024, 256, 0, stream>>>((float*)p1h, (long)NG * (KP1 / 2));

    const int nb = (N + SCB - 1) / SCB;

    for (int enc = 0; enc < 2; ++enc) {
        const int* x  = (const int*)d_in[enc * 4 + 0];
        const int* ei = (const int*)d_in[enc * 4 + 1];
        const int* ea = (const int*)d_in[enc * 4 + 2];
        const int* bi = (const int*)d_in[enc * 4 + 3];

        zero_i32_v8<<<256, 256, 0, stream>>>(deg, N);
        hist_dst_v8<<<1024, 256, 0, stream>>>(ei, deg, E);
        scan_bsum_v10<<<nb, 256, 0, stream>>>(deg, bsum, N);
        scan_top_v10<<<1, 256, 0, stream>>>(bsum, nb, rp + N);
        scan_fill_v10<<<nb, 256, 0, stream>>>(deg, bsum, rp, N);
        copy_i32_v8<<<256, 256, 0, stream>>>(rp, cursor, N);
        fill_csr_v8<<<1024, 256, 0, stream>>>(ei, ea, cursor, csrc, ccombo, E);
        zero_i32_v8<<<64, 256, 0, stream>>>(gdeg, NG);
        hist_b_v8<<<1024, 256, 0, stream>>>(bi, gdeg, N);
        scan_excl_v8<<<1, 256, 0, stream>>>(gdeg, gptr, NG);

        unsigned char* hc = h0;
        unsigned char* hn = h1;
        init_h_v22<<<4096, 256, 0, stream>>>(x, atom1, atom2, hc, N);

        for (int l = 0; l < NLAYERS; ++l) {
            const unsigned char* W1l = W1t8 + (size_t)l * NHID * KP1;
            const unsigned char* W2l = W2t8 + (size_t)l * EMB * KP2;
            const float* tl = tbl + (size_t)l * NCOMBO * EMB;
            const float* scp = scl + (size_t)(l - 1) * EMB;
            const float* sfp = sft + (size_t)(l - 1) * EMB;

            zero_f32_v6<<<1, 1024, 0, stream>>>(sums, 2 * EMB);

            for (long c0 = 0; c0 < N; c0 += CN) {
                int m = (int)((N - c0 < CN) ? (N - c0) : CN);
                if (l == 0)
                    gather_v18<false><<<2048, 256, 0, stream>>>(
                        hc, rp, csrc, ccombo, tl, nullptr, nullptr,
                        aggc, (int)c0, (int)(c0 + m));
                else
                    gather_v18<true><<<2048, 256, 0, stream>>>(
                        hc, rp, csrc, ccombo, tl, scp, sfp,
                        aggc, (int)c0, (int)(c0 + m));
                int gx1 = (NHID + 127) / 128, gy1 = (m + 127) / 128;
                fast_gemm8_v20<2, false><<<gx1 * gy1, 256, 0, stream>>>(
                    aggc, KP1, W1l, KP1, bm1 + l * NHID,
                    z, KP2, m, NHID, KP1, gx1, nullptr);
                int gx2 = (EMB + 127) / 128;
                fast_gemm8_v20<1, true><<<gx2 * gy1, 256, 0, stream>>>(
                    z, KP2, W2l, KP2, bm2 + l * EMB,
                    hn + (size_t)c0 * HS, HS, m, EMB, KP2, gx2, sums);
            }

            bn_finalize_v6<<<1, 320, 0, stream>>>(sums, gamma + l * EMB, beta + l * EMB,
                                                  scl + (size_t)l * EMB,
                                                  sft + (size_t)l * EMB, 1.f / (float)N);
            unsigned char* t = hc; hc = hn; hn = t;
        }
        // NLAYERS=5 (odd): final raw state in h1; h0 (d_out overlay) dead.

        pool_seg_v11<<<NG, 256, 0, stream>>>(hc, gptr,
                                             scl + (size_t)(NLAYERS - 1) * EMB,
                                             sft + (size_t)(NLAYERS - 1) * EMB, poolh);

        dim3 gp((EMB + 127) / 128, (NG + 127) / 128);
        fast_gemm_v12<__half, 2><<<gp, 256, 0, stream>>>(
            (const f16t*)poolh, KP1, Wp1t, KP1, bp1, p1h, KP1, NG, EMB, KP1, 1.f);
        fast_gemm_v12<float, 1><<<gp, 256, 0, stream>>>(
            (const f16t*)p1h, KP1, Wp2t, KP1, bp2, fbuf, EMB, NG, EMB, KP1, 1.f);
        rownorm_f16_v12<<<NG, 256, 0, stream>>>(fbuf, fh + (size_t)enc * NG * KP1);
    }

    // logits = (f0h @ f1h^T) * 25, clamped, f16 MFMA; then labels
    f16t* f0h = fh;
    f16t* f1h = fh + (size_t)NG * KP1;
    dim3 gl(NG / 128, NG / 128);
    fast_gemm_v12<float, 3><<<gl, 256, 0, stream>>>(
        f0h, KP1, f1h, KP1, nullptr, ob, NG, NG, NG, KP1, 25.f);
    labels_v6<<<(NG + 255) / 256, 256, 0, stream>>>(ob + (size_t)NG * NG, NG);
}